// Round 6
// baseline (309.387 us; speedup 1.0000x reference)
//
#include <hip/hip_runtime.h>
#include <hip/hip_bf16.h>

#define K2 2520
#define PROJ 1024
#define HID 184
#define N1F (512.f*63.f*46.f)
#define N2F (512.f*46.f)

typedef float f32x4 __attribute__((ext_vector_type(4)));
typedef short bf16x8 __attribute__((ext_vector_type(8)));
typedef unsigned short u16;
typedef unsigned short ushort8 __attribute__((ext_vector_type(8)));

__device__ __forceinline__ u16 f2bf(float f) {   // RNE fp32 -> bf16 bits
    unsigned u = __builtin_bit_cast(unsigned, f);
    return (u16)((u + 0x7FFFu + ((u >> 16) & 1u)) >> 16);
}
__device__ __forceinline__ float bf2f(u16 h) {
    unsigned u = ((unsigned)h) << 16;
    return __builtin_bit_cast(float, u);
}

// ---------------- kX: merged weight prep + stats zero ----------------
__global__ void kX(const float* __restrict__ W, const float* __restrict__ w2,
                   const float* __restrict__ fw1, const float* __restrict__ fw2,
                   u16* __restrict__ Wbf, u16* __restrict__ Wbf2,
                   u16* __restrict__ fwbf1, u16* __restrict__ fwbf2, float* stats) {
    int bid = blockIdx.x, tid = threadIdx.x;
    if (bid == 0 && tid < 320) stats[tid] = 0.f;
    if (bid < 2560) {
        int i = bid*256 + tid;
        int sj = i >> 16, s_ = (i >> 8) & 255, t_ = i & 255;
        float v = (s_ < 250 && t_ < 250) ? W[(size_t)sj*62500 + s_*250 + t_] : 0.f;
        Wbf[i] = f2bf(v);
    } else if (bid < 3034) {
        int i = (bid-2560)*256 + tid;
        int n = i / 2528, k = i - n*2528;
        float v = 0.f;
        if (n < 40 && k < K2) { int c = k/40, o = k - c*40; v = w2[n*K2 + o*63 + c]; }
        Wbf2[i] = f2bf(v);
    } else if (bid < 3802) {
        int i = (bid-3034)*256 + tid;
        int n = i/192, k = i - n*192;
        fwbf1[i] = f2bf(k < HID ? fw1[n*HID + k] : 0.f);
    } else {
        int i = (bid-3802)*256 + tid;
        fwbf2[i] = f2bf(fw2[i]);
    }
}

// ---------------- kAB: subject-matmul (MFMA) + o-tiled fp32 conv+pool -------------------
// grid (512 b, 2 c-halves), block 256. pooled [b][w][k], k = c*40+o. bn1 partial sums.
// Phase 2: thread = (c2 in [0,32), og in [0,8)); each thread: 1 c-row x 5 output channels.
// 5 LDS reads feed 105 FMA per w-step (was 5 reads / 21 FMA with 40x row redundancy).
#define XS(c,s) xs[(c)*258 + (s)]
__global__ __launch_bounds__(256) void kAB(const float* __restrict__ x,
                                           const int* __restrict__ subj,
                                           const u16* __restrict__ Wbf,
                                           const float* __restrict__ bsub,
                                           const float* __restrict__ w1,
                                           const float* __restrict__ b1,
                                           u16* __restrict__ pooled,
                                           float* __restrict__ stats) {
    __shared__ float xs[32 * 258];      // 33,024 B
    __shared__ float effs[40 * 22];
    __shared__ float biasL[256];
    __shared__ float sS[4][8][5], sQ[4][8][5];
    int b = blockIdx.x, ch = blockIdx.y;
    int sj = subj[b];
    int tid = threadIdx.x;
    int wv = tid >> 6, lane = tid & 63, row = lane & 15, kg = lane >> 4;

    // ---- phase 0: bias row + effective 21-tap filter (fp32)
    biasL[tid] = (tid < 250) ? bsub[sj*250 + tid] : 0.f;
    for (int i = tid; i < 840; i += 256) {
        int o = i / 21, j = i - o * 21;
        float e = 0.f;
        #pragma unroll
        for (int k = 0; k < 5; ++k) { int u = j - k; if (u >= 0 && u <= 16) e += w1[o*5+k]; }
        effs[o*22 + j] = e * (1.f / 17.f);
    }

    // ---- phase 1: MFMA x_eeg rows (c) x cols (s); wave = (cgrp, nf-half)
    int cgrp = wv & 1, nfh = wv >> 1;
    int cglob = ch*32 + cgrp*16 + row;
    const float* xr = x + ((size_t)b*63 + (cglob < 63 ? cglob : 62))*250;
    const u16* Wb = Wbf + (size_t)sj*65536;
    f32x4 acc[8];
    #pragma unroll
    for (int i = 0; i < 8; ++i) acc[i] = (f32x4){0.f,0.f,0.f,0.f};
    #pragma unroll
    for (int ks = 0; ks < 8; ++ks) {
        int tb = ks*32 + kg*8;
        float av[8];
        if (ks < 7) {
            #pragma unroll
            for (int j = 0; j < 8; j += 2) { float2 v = *(const float2*)&xr[tb+j]; av[j]=v.x; av[j+1]=v.y; }
        } else {
            #pragma unroll
            for (int j = 0; j < 8; ++j) av[j] = 0.f;
            if (kg < 3) {
                #pragma unroll
                for (int j = 0; j < 8; j += 2) { float2 v = *(const float2*)&xr[tb+j]; av[j]=v.x; av[j+1]=v.y; }
            } else {
                float2 v = *(const float2*)&xr[248]; av[0]=v.x; av[1]=v.y;
            }
        }
        bf16x8 af;
        #pragma unroll
        for (int j = 0; j < 8; ++j) af[j] = (short)f2bf(av[j]);
        #pragma unroll
        for (int nf2 = 0; nf2 < 8; ++nf2) {
            int nf = nfh*8 + nf2;
            bf16x8 bv = *(const bf16x8*)(Wb + (size_t)(nf*16 + row)*256 + tb);
            acc[nf2] = __builtin_amdgcn_mfma_f32_16x16x32_bf16(af, bv, acc[nf2], 0, 0, 0);
        }
    }
    __syncthreads();    // biasL/effs ready; now write tile to LDS (fp32)
    int cw = cgrp*16 + kg*4;
    #pragma unroll
    for (int nf2 = 0; nf2 < 8; ++nf2) {
        int s = (nfh*8 + nf2)*16 + row;
        float bias = biasL[s];
        #pragma unroll
        for (int r = 0; r < 4; ++r) XS(cw + r, s) = acc[nf2][r] + bias;
    }
    __syncthreads();

    // ---- phase 2: o-tiled conv+pool
    int c2 = tid >> 3, og = tid & 7;
    bool rowvalid = (ch == 0) || (c2 < 31);
    float eff[5][21];
    float bo[5];
    #pragma unroll
    for (int i = 0; i < 5; ++i) {
        int o = og*5 + i;
        bo[i] = b1[o];
        #pragma unroll
        for (int j = 0; j < 21; ++j) eff[i][j] = effs[o*22 + j];
    }
    float ssum[5] = {0.f,0.f,0.f,0.f,0.f}, ssq[5] = {0.f,0.f,0.f,0.f,0.f};
    if (rowvalid) {
        float win[21];
        #pragma unroll
        for (int j = 0; j < 21; ++j) win[j] = XS(c2, j);
        u16* prow = pooled + (size_t)b*46*K2 + (ch*32 + c2)*40 + og*5;
        for (int w = 0; w < 46; ++w) {
            float a[5];
            #pragma unroll
            for (int i = 0; i < 5; ++i) {
                float s = bo[i];
                #pragma unroll
                for (int j = 0; j < 21; ++j) s = fmaf(win[j], eff[i][j], s);
                a[i] = s;
            }
            #pragma unroll
            for (int i = 0; i < 5; ++i) {
                prow[(size_t)w*K2 + i] = f2bf(a[i]);
                ssum[i] += a[i];
                ssq[i] = fmaf(a[i], a[i], ssq[i]);
            }
            if (w < 45) {
                #pragma unroll
                for (int j2 = 0; j2 < 16; ++j2) win[j2] = win[j2+5];
                #pragma unroll
                for (int j2 = 16; j2 < 21; ++j2) win[j2] = XS(c2, 5*w + 5 + j2);
            }
        }
    }
    // reduce over c2: lanes same og are stride-8 within wave (c2 bits = lane>>3)
    #pragma unroll
    for (int i = 0; i < 5; ++i) {
        float s = ssum[i], q = ssq[i];
        s += __shfl_xor(s, 8);  q += __shfl_xor(q, 8);
        s += __shfl_xor(s, 16); q += __shfl_xor(q, 16);
        s += __shfl_xor(s, 32); q += __shfl_xor(q, 32);
        if ((lane >> 3) == 0) { sS[wv][lane][i] = s; sQ[wv][lane][i] = q; }
    }
    __syncthreads();
    if (tid < 40) {
        int og2 = tid / 5, i2 = tid - og2*5;
        float s = sS[0][og2][i2] + sS[1][og2][i2] + sS[2][og2][i2] + sS[3][og2][i2];
        float q = sQ[0][og2][i2] + sQ[1][og2][i2] + sQ[2][og2][i2] + sQ[3][og2][i2];
        atomicAdd(&stats[tid], s);
        atomicAdd(&stats[40 + tid], q);
    }
}

// ---------------- kD: bn1 finalize + out2 = elu(bn1(pooled)) @ w2^T + b2 + bn2 sums ----
// grid 736 (m-tiles of 32), block 256: waves {rowgrp 0,1} x {khalf 0,1}.
__global__ __launch_bounds__(256) void kD(const u16* __restrict__ pooled,
                                          const u16* __restrict__ Wbf2,
                                          const float* __restrict__ b2,
                                          const float* __restrict__ g1,
                                          const float* __restrict__ bb1,
                                          const float* __restrict__ stats,
                                          float* __restrict__ out2,
                                          float* __restrict__ statw) {
    __shared__ float2 scsh[40];
    __shared__ float mrg[2][64][12];
    __shared__ float redS[2][48], redQ[2][48];
    int tid = threadIdx.x;
    if (tid < 40) {
        float mean = stats[tid] / N1F;
        float var  = stats[40 + tid] / N1F - mean * mean;
        float sc   = g1[tid] * rsqrtf(var + 1e-5f);
        scsh[tid] = make_float2(sc, bb1[tid] - mean * sc);
    }
    __syncthreads();
    int wv = tid >> 6, lane = tid & 63, row = lane & 15, kg = lane >> 4;
    int rowgrp = wv >> 1, khalf = wv & 1;
    int mbase = blockIdx.x*32 + rowgrp*16;
    const u16* pr = pooled + (size_t)(mbase + row) * K2;
    f32x4 acc[3];
    #pragma unroll
    for (int i = 0; i < 3; ++i) acc[i] = (f32x4){0.f,0.f,0.f,0.f};

    int ksBeg = khalf ? 39 : 0, ksEnd = khalf ? 79 : 39;
    for (int ks = ksBeg; ks < ksEnd; ++ks) {
        int kbase = ks*32 + kg*8;
        ushort8 cur = *(const ushort8*)&pr[kbase];
        bf16x8 bv0 = *(const bf16x8*)(Wbf2 + (size_t)(row     )*2528 + kbase);
        bf16x8 bv1 = *(const bf16x8*)(Wbf2 + (size_t)(16 + row)*2528 + kbase);
        bf16x8 bv2 = *(const bf16x8*)(Wbf2 + (size_t)(32 + row)*2528 + kbase);
        bf16x8 af;
        bool valid = (ks < 78) | (kg < 3);
        if (valid) {
            #pragma unroll
            for (int j = 0; j < 8; ++j) {
                int k = kbase + j;
                int u = (k * 1639) >> 16;            // k/40 for k<2731
                int o = k - u*40;
                float2 sshf = scsh[o];
                float a = fmaf(bf2f(cur[j]), sshf.x, sshf.y);
                float e = a > 0.f ? a : __expf(a) - 1.f;
                af[j] = (short)f2bf(e);
            }
        } else {
            #pragma unroll
            for (int j = 0; j < 8; ++j) af[j] = 0;
        }
        acc[0] = __builtin_amdgcn_mfma_f32_16x16x32_bf16(af, bv0, acc[0], 0, 0, 0);
        acc[1] = __builtin_amdgcn_mfma_f32_16x16x32_bf16(af, bv1, acc[1], 0, 0, 0);
        acc[2] = __builtin_amdgcn_mfma_f32_16x16x32_bf16(af, bv2, acc[2], 0, 0, 0);
    }

    if (khalf) {
        #pragma unroll
        for (int nf = 0; nf < 3; ++nf)
            #pragma unroll
            for (int r = 0; r < 4; ++r) mrg[rowgrp][lane][nf*4 + r] = acc[nf][r];
    }
    __syncthreads();
    if (!khalf) {
        float sN[3] = {0.f,0.f,0.f}, qN[3] = {0.f,0.f,0.f};
        #pragma unroll
        for (int nf = 0; nf < 3; ++nf) {
            int n = nf*16 + row;
            #pragma unroll
            for (int r = 0; r < 4; ++r) acc[nf][r] += mrg[rowgrp][lane][nf*4 + r];
            if (n < 40) {
                float bias = b2[n];
                #pragma unroll
                for (int r = 0; r < 4; ++r) {
                    float v = acc[nf][r] + bias;
                    out2[(size_t)(mbase + kg*4 + r)*40 + n] = v;
                    sN[nf] += v; qN[nf] += v*v;
                }
            }
        }
        #pragma unroll
        for (int nf = 0; nf < 3; ++nf) {
            float s = sN[nf], q = qN[nf];
            s += __shfl_xor(s, 16); q += __shfl_xor(q, 16);
            s += __shfl_xor(s, 32); q += __shfl_xor(q, 32);
            if (kg == 0) { redS[rowgrp][nf*16 + row] = s; redQ[rowgrp][nf*16 + row] = q; }
        }
    }
    __syncthreads();
    if (tid < 40) {
        atomicAdd(&statw[160 + tid], redS[0][tid] + redS[1][tid]);
        atomicAdd(&statw[200 + tid], redQ[0][tid] + redQ[1][tid]);
    }
}

// ---------------- kF: bn2 finalize + bn2+elu+proj -> z bf16 [512][192] ----------------
__global__ void kF(const float* __restrict__ out2, const float* __restrict__ stats,
                   const float* __restrict__ g2, const float* __restrict__ bb2,
                   const float* __restrict__ pw, const float* __restrict__ pb,
                   u16* __restrict__ zbf) {
    int b = blockIdx.x, t = threadIdx.x;
    __shared__ float sc[40], sh[40], pws[160];
    __shared__ float o2[1840];
    if (t < 40) {
        float mean = stats[160 + t] / N2F;
        float var  = stats[200 + t] / N2F - mean * mean;
        float s    = g2[t] * rsqrtf(var + 1e-5f);
        sc[t] = s;
        sh[t] = bb2[t] - mean * s;
    }
    if (t < 160) pws[t] = pw[t];
    for (int i = t; i < 1840; i += 256) o2[i] = out2[(size_t)b*1840 + i];
    __syncthreads();
    if (t < 192) {
        float accv = 0.f;
        if (t < HID) {
            int w = t >> 2, e = t & 3;
            accv = pb[e];
            for (int o = 0; o < 40; ++o) {
                float a = o2[w*40 + o];
                float act = a * sc[o] + sh[o];
                act = act > 0.f ? act : __expf(act) - 1.f;
                accv = fmaf(act, pws[e*40 + o], accv);
            }
        }
        zbf[(size_t)b*192 + t] = f2bf(accv);
    }
}

// ---------------- kG1: h1 = z @ fc1_w^T + b (MFMA); g = gelu(h1) bf16 ----------------
__global__ __launch_bounds__(256) void kG1(const u16* __restrict__ zbf, const u16* __restrict__ fwbf1,
                                           const float* __restrict__ fb,
                                           float* __restrict__ h1, u16* __restrict__ gbf) {
    int n0 = blockIdx.x * 64, m0 = blockIdx.y * 16;
    int tid = threadIdx.x, wv = tid >> 6, lane = tid & 63, row = lane & 15, kg = lane >> 4;
    const u16* zr = zbf + (size_t)(m0 + row) * 192;
    const u16* wr = fwbf1 + (size_t)(n0 + wv*16 + row) * 192;
    f32x4 acc = (f32x4){0.f,0.f,0.f,0.f};
    #pragma unroll
    for (int ks = 0; ks < 6; ++ks) {
        bf16x8 av = *(const bf16x8*)(zr + ks*32 + kg*8);
        bf16x8 bv = *(const bf16x8*)(wr + ks*32 + kg*8);
        acc = __builtin_amdgcn_mfma_f32_16x16x32_bf16(av, bv, acc, 0, 0, 0);
    }
    int n = n0 + wv*16 + row;
    float bias = fb[n];
    #pragma unroll
    for (int r = 0; r < 4; ++r) {
        int m = m0 + kg*4 + r;
        float v = acc[r] + bias;
        h1[(size_t)m*PROJ + n] = v;
        float ge = 0.5f * v * (1.f + erff(v * 0.70710678118f));
        gbf[(size_t)m*PROJ + n] = f2bf(ge);
    }
}

// ---------------- kG2: h2 = h1 + g @ fc2_w^T + b (MFMA) ----------------
__global__ __launch_bounds__(256) void kG2(const u16* __restrict__ gbf, const u16* __restrict__ fwbf,
                                           const float* __restrict__ fb, const float* __restrict__ h1,
                                           float* __restrict__ h2) {
    int n0 = blockIdx.x * 32, m0 = blockIdx.y * 64;
    int tid = threadIdx.x;
    int wv = tid >> 6, lane = tid & 63, row = lane & 15, kg = lane >> 4;
    const u16* gr = gbf + (size_t)(m0 + wv*16 + row) * PROJ;
    f32x4 acc[2];
    #pragma unroll
    for (int i = 0; i < 2; ++i) acc[i] = (f32x4){0.f,0.f,0.f,0.f};
    for (int ks = 0; ks < 32; ++ks) {
        int kbase = ks*32 + kg*8;
        bf16x8 av  = *(const bf16x8*)(gr + kbase);
        bf16x8 bv0 = *(const bf16x8*)(fwbf + (size_t)(n0      + row)*PROJ + kbase);
        bf16x8 bv1 = *(const bf16x8*)(fwbf + (size_t)(n0 + 16 + row)*PROJ + kbase);
        acc[0] = __builtin_amdgcn_mfma_f32_16x16x32_bf16(av, bv0, acc[0], 0, 0, 0);
        acc[1] = __builtin_amdgcn_mfma_f32_16x16x32_bf16(av, bv1, acc[1], 0, 0, 0);
    }
    int m = m0 + wv*16 + kg*4;
    #pragma unroll
    for (int nf = 0; nf < 2; ++nf) {
        int n = n0 + nf*16 + row;
        float bias = fb[n];
        #pragma unroll
        for (int r = 0; r < 4; ++r)
            h2[(size_t)(m + r)*PROJ + n] = acc[nf][r] + bias + h1[(size_t)(m + r)*PROJ + n];
    }
}

// ---------------- kG3: LayerNorm rows of 1024 ----------------
__global__ __launch_bounds__(256) void kG3(const float* __restrict__ h2, const float* __restrict__ lg,
                                           const float* __restrict__ lb, float* __restrict__ out) {
    int b = blockIdx.x, tid = threadIdx.x;
    float4 v = *(const float4*)&h2[(size_t)b*PROJ + tid*4];
    float s = v.x + v.y + v.z + v.w;
    float q = v.x*v.x + v.y*v.y + v.z*v.z + v.w*v.w;
    __shared__ float ps[4], pq[4], mb[2];
    int wave = tid >> 6, lane = tid & 63;
    #pragma unroll
    for (int d = 32; d >= 1; d >>= 1) { s += __shfl_down(s, d); q += __shfl_down(q, d); }
    if (lane == 0) { ps[wave] = s; pq[wave] = q; }
    __syncthreads();
    if (tid == 0) {
        float S = ps[0]+ps[1]+ps[2]+ps[3], Q = pq[0]+pq[1]+pq[2]+pq[3];
        float mean = S / 1024.f, var = Q / 1024.f - mean*mean;
        mb[0] = mean; mb[1] = rsqrtf(var + 1e-5f);
    }
    __syncthreads();
    float mean = mb[0], inv = mb[1];
    float4 g4 = *(const float4*)&lg[tid*4];
    float4 b4 = *(const float4*)&lb[tid*4];
    float4 o4;
    o4.x = (v.x - mean)*inv*g4.x + b4.x;
    o4.y = (v.y - mean)*inv*g4.y + b4.y;
    o4.z = (v.z - mean)*inv*g4.z + b4.z;
    o4.w = (v.w - mean)*inv*g4.w + b4.w;
    *(float4*)&out[(size_t)b*PROJ + tid*4] = o4;
}

extern "C" void kernel_launch(void* const* d_in, const int* in_sizes, int n_in,
                              void* d_out, int out_size, void* d_ws, size_t ws_size,
                              hipStream_t stream) {
    const float* x       = (const float*)d_in[0];
    const int*   subjects= (const int*)  d_in[1];
    const float* W_subj  = (const float*)d_in[2];
    const float* b_subj  = (const float*)d_in[3];
    const float* conv1_w = (const float*)d_in[4];
    const float* conv1_b = (const float*)d_in[5];
    const float* bn1_g   = (const float*)d_in[6];
    const float* bn1_b   = (const float*)d_in[7];
    const float* conv2_w = (const float*)d_in[8];
    const float* conv2_b = (const float*)d_in[9];
    const float* bn2_g   = (const float*)d_in[10];
    const float* bn2_b   = (const float*)d_in[11];
    const float* proj_w  = (const float*)d_in[12];
    const float* proj_b  = (const float*)d_in[13];
    const float* fc1_w   = (const float*)d_in[14];
    const float* fc1_b   = (const float*)d_in[15];
    const float* fc2_w   = (const float*)d_in[16];
    const float* fc2_b   = (const float*)d_in[17];
    const float* ln_g    = (const float*)d_in[18];
    const float* ln_b    = (const float*)d_in[19];
    float* out = (float*)d_out;

    char* ws = (char*)d_ws;
    u16*   pooled = (u16*)  ws;                      // 118,702,080 B
    float* out2   = (float*)(ws + 118702144);        // 3,768,320 B
    u16*   zbf    = (u16*)  (ws + 122470464);        // 196,608 B
    float* h1     = (float*)(ws + 122667072);        // 2,097,152 B
    float* h2     = (float*)(ws + 124764224);        // 2,097,152 B
    u16*   gbf    = (u16*)  (ws + 126861376);        // 1,048,576 B
    float* stats  = (float*)(ws + 127909952);        // 1,280 B (pad 4096)
    u16*   Wbf    = (u16*)  (ws + 127914048);        // 1,310,720 B
    u16*   Wbf2   = (u16*)  (ws + 129224768);        // 242,688 B
    u16*   fwbf2  = (u16*)  (ws + 129467456);        // 2,097,152 B
    u16*   fwbf1  = (u16*)  (ws + 131564608);        // 393,216 B

    kX  <<<7898, 256, 0, stream>>>(W_subj, conv2_w, fc1_w, fc2_w, Wbf, Wbf2, fwbf1, fwbf2, stats);
    kAB <<<dim3(512, 2), 256, 0, stream>>>(x, subjects, Wbf, b_subj, conv1_w, conv1_b, pooled, stats);
    kD  <<<736, 256, 0, stream>>>(pooled, Wbf2, conv2_b, bn1_g, bn1_b, stats, out2, stats);
    kF  <<<512, 256, 0, stream>>>(out2, stats, bn2_g, bn2_b, proj_w, proj_b, zbf);
    kG1 <<<dim3(16, 32), 256, 0, stream>>>(zbf, fwbf1, fc1_b, h1, gbf);
    kG2 <<<dim3(32, 8), 256, 0, stream>>>(gbf, fwbf2, fc2_b, h1, h2);
    kG3 <<<512, 256, 0, stream>>>(h2, ln_g, ln_b, out);
    (void)in_sizes; (void)n_in; (void)out_size; (void)ws_size;
}

// Round 7
// 282.510 us; speedup vs baseline: 1.0951x; 1.0951x over previous
//
#include <hip/hip_runtime.h>
#include <hip/hip_bf16.h>

#define K2 2520
#define PROJ 1024
#define HID 184
#define N1F (512.f*63.f*46.f)
#define N2F (512.f*46.f)

typedef float f32x4 __attribute__((ext_vector_type(4)));
typedef short bf16x8 __attribute__((ext_vector_type(8)));
typedef unsigned short u16;
typedef unsigned short ushort8 __attribute__((ext_vector_type(8)));
typedef unsigned int u32;
typedef unsigned int u32x4 __attribute__((ext_vector_type(4)));

__device__ __forceinline__ u16 f2bf(float f) {   // RNE fp32 -> bf16 bits
    unsigned u = __builtin_bit_cast(unsigned, f);
    return (u16)((u + 0x7FFFu + ((u >> 16) & 1u)) >> 16);
}
__device__ __forceinline__ float bf2f(u16 h) {
    unsigned u = ((unsigned)h) << 16;
    return __builtin_bit_cast(float, u);
}
__device__ __forceinline__ u32 cvtpk(float lo, float hi) {  // bf16(lo) | bf16(hi)<<16
    u32 r;
    asm("v_cvt_pk_bf16_f32 %0, %1, %2" : "=v"(r) : "v"(lo), "v"(hi));
    return r;
}

// ---------------- kX: merged weight prep + stats zero ----------------
__global__ void kX(const float* __restrict__ W, const float* __restrict__ w2,
                   const float* __restrict__ fw1, const float* __restrict__ fw2,
                   u16* __restrict__ Wbf, u16* __restrict__ Wbf2,
                   u16* __restrict__ fwbf1, u16* __restrict__ fwbf2, float* stats) {
    int bid = blockIdx.x, tid = threadIdx.x;
    if (bid == 0 && tid < 320) stats[tid] = 0.f;
    if (bid < 2560) {
        int i = bid*256 + tid;
        int sj = i >> 16, s_ = (i >> 8) & 255, t_ = i & 255;
        float v = (s_ < 250 && t_ < 250) ? W[(size_t)sj*62500 + s_*250 + t_] : 0.f;
        Wbf[i] = f2bf(v);
    } else if (bid < 3034) {
        int i = (bid-2560)*256 + tid;
        int n = i / 2528, k = i - n*2528;
        float v = 0.f;
        if (n < 40 && k < K2) { int c = k/40, o = k - c*40; v = w2[n*K2 + o*63 + c]; }
        Wbf2[i] = f2bf(v);
    } else if (bid < 3802) {
        int i = (bid-3034)*256 + tid;
        int n = i/192, k = i - n*192;
        fwbf1[i] = f2bf(k < HID ? fw1[n*HID + k] : 0.f);
    } else {
        int i = (bid-3802)*256 + tid;
        fwbf2[i] = f2bf(fw2[i]);
    }
}

// ---------------- kAB: subject-matmul (MFMA) + hi/lo-split MFMA conv+pool ---------------
// grid (512 b, 2 c-halves), block 256. pooled [b][w][k], k = c*40+o. bn1 partial sums.
// Phase 2: per c-row, 46x40x21 GEMM via 16x16x32 MFMA with bf16 hi/lo error compensation:
//   conv = x_hi*e_hi + x_hi*e_lo + x_lo*e_hi  (+bias via C-in); fp32-grade accuracy.
#define XS(c,s) xs[(c)*258 + (s)]
__global__ __launch_bounds__(256) void kAB(const float* __restrict__ x,
                                           const int* __restrict__ subj,
                                           const u16* __restrict__ Wbf,
                                           const float* __restrict__ bsub,
                                           const float* __restrict__ w1,
                                           const float* __restrict__ b1,
                                           u16* __restrict__ pooled,
                                           float* __restrict__ stats) {
    __shared__ float xs[32*258 + 16];   // fp32 x_eeg tile, cols [250,258)+tail zeroed
    __shared__ u16 effh[48*32] __attribute__((aligned(16)));
    __shared__ u16 effl[48*32] __attribute__((aligned(16)));
    __shared__ float biasL[256];
    __shared__ float sS[4][48], sQ[4][48];
    int b = blockIdx.x, ch = blockIdx.y;
    int sj = subj[b];
    int tid = threadIdx.x;
    int wv = tid >> 6, lane = tid & 63, row = lane & 15, kg = lane >> 4;

    // ---- phase 0: bias row + hi/lo effective 21-tap filter (K padded to 32) + xs pads
    biasL[tid] = (tid < 250) ? bsub[sj*250 + tid] : 0.f;
    for (int i = tid; i < 1536; i += 256) {
        int o = i >> 5, tap = i & 31;
        float e = 0.f;
        if (o < 40 && tap < 21) {
            #pragma unroll
            for (int k = 0; k < 5; ++k) { int u = tap - k; if (u >= 0 && u <= 16) e += w1[o*5+k]; }
            e *= (1.f/17.f);
        }
        u16 h = f2bf(e);
        effh[i] = h;
        effl[i] = f2bf(e - bf2f(h));
    }
    {   // zero xs pad: cols [250,258) of 32 rows + 16-float tail
        int r = tid >> 3, cc = tid & 7;
        XS(r, 250 + cc) = 0.f;
        if (tid < 16) xs[32*258 + tid] = 0.f;
    }

    // ---- phase 1: MFMA x_eeg rows (c) x cols (s); wave = (cgrp, nf-half)
    int cgrp = wv & 1, nfh = wv >> 1;
    int cglob = ch*32 + cgrp*16 + row;
    const float* xr = x + ((size_t)b*63 + (cglob < 63 ? cglob : 62))*250;
    const u16* Wb = Wbf + (size_t)sj*65536;
    f32x4 acc[8];
    #pragma unroll
    for (int i = 0; i < 8; ++i) acc[i] = (f32x4){0.f,0.f,0.f,0.f};
    #pragma unroll
    for (int ks = 0; ks < 8; ++ks) {
        int tb = ks*32 + kg*8;
        float av[8];
        if (ks < 7) {
            #pragma unroll
            for (int j = 0; j < 8; j += 2) { float2 v = *(const float2*)&xr[tb+j]; av[j]=v.x; av[j+1]=v.y; }
        } else {
            #pragma unroll
            for (int j = 0; j < 8; ++j) av[j] = 0.f;
            if (kg < 3) {
                #pragma unroll
                for (int j = 0; j < 8; j += 2) { float2 v = *(const float2*)&xr[tb+j]; av[j]=v.x; av[j+1]=v.y; }
            } else {
                float2 v = *(const float2*)&xr[248]; av[0]=v.x; av[1]=v.y;
            }
        }
        bf16x8 af;
        #pragma unroll
        for (int j = 0; j < 8; ++j) af[j] = (short)f2bf(av[j]);
        #pragma unroll
        for (int nf2 = 0; nf2 < 8; ++nf2) {
            int nf = nfh*8 + nf2;
            bf16x8 bv = *(const bf16x8*)(Wb + (size_t)(nf*16 + row)*256 + tb);
            acc[nf2] = __builtin_amdgcn_mfma_f32_16x16x32_bf16(af, bv, acc[nf2], 0, 0, 0);
        }
    }
    __syncthreads();    // biasL/eff/pads ready; write tile to LDS (fp32)
    int cw = cgrp*16 + kg*4;
    #pragma unroll
    for (int nf2 = 0; nf2 < 8; ++nf2) {
        int s = (nfh*8 + nf2)*16 + row;
        float bias = biasL[s];
        #pragma unroll
        for (int r = 0; r < 4; ++r) XS(cw + r, s) = acc[nf2][r] + bias;
    }
    __syncthreads();

    // ---- phase 2: hi/lo MFMA conv+pool
    bf16x8 bvh[3], bvl[3];
    float b1v[3];
    bool ovalid[3];
    #pragma unroll
    for (int nt = 0; nt < 3; ++nt) {
        bvh[nt] = *(const bf16x8*)(effh + (nt*16 + row)*32 + kg*8);
        bvl[nt] = *(const bf16x8*)(effl + (nt*16 + row)*32 + kg*8);
        int o = nt*16 + row;
        ovalid[nt] = o < 40;
        b1v[nt] = ovalid[nt] ? b1[o] : 0.f;
    }
    float ss[3] = {0.f,0.f,0.f}, sq[3] = {0.f,0.f,0.f};
    int climit = ch ? 31 : 32;
    for (int c2 = wv; c2 < climit; c2 += 4) {
        f32x4 acc2[3][3];
        #pragma unroll
        for (int mt = 0; mt < 3; ++mt) {
            int base = c2*258 + 5*(mt*16 + row) + kg*8;
            float av[8];
            #pragma unroll
            for (int j = 0; j < 8; ++j) av[j] = xs[base + j];
            u32x4 ph, pl;
            #pragma unroll
            for (int p = 0; p < 4; ++p) {
                u32 h = cvtpk(av[2*p], av[2*p+1]);
                float h0 = __builtin_bit_cast(float, h << 16);
                float h1 = __builtin_bit_cast(float, h & 0xFFFF0000u);
                ph[p] = h;
                pl[p] = cvtpk(av[2*p] - h0, av[2*p+1] - h1);
            }
            bf16x8 afh = __builtin_bit_cast(bf16x8, ph);
            bf16x8 afl = __builtin_bit_cast(bf16x8, pl);
            #pragma unroll
            for (int nt = 0; nt < 3; ++nt) {
                f32x4 a = (f32x4){b1v[nt], b1v[nt], b1v[nt], b1v[nt]};
                a = __builtin_amdgcn_mfma_f32_16x16x32_bf16(afl, bvh[nt], a, 0, 0, 0);
                a = __builtin_amdgcn_mfma_f32_16x16x32_bf16(afh, bvl[nt], a, 0, 0, 0);
                a = __builtin_amdgcn_mfma_f32_16x16x32_bf16(afh, bvh[nt], a, 0, 0, 0);
                acc2[mt][nt] = a;
            }
        }
        u16* prow = pooled + (size_t)b*46*K2 + (ch*32 + c2)*40;
        #pragma unroll
        for (int mt = 0; mt < 3; ++mt) {
            #pragma unroll
            for (int nt = 0; nt < 3; ++nt) {
                if (!ovalid[nt]) continue;
                int o = nt*16 + row;
                #pragma unroll
                for (int r = 0; r < 4; ++r) {
                    int w = mt*16 + kg*4 + r;
                    if (mt < 2 || w < 46) {
                        float v = acc2[mt][nt][r];
                        prow[(size_t)w*K2 + o] = f2bf(v);
                        ss[nt] += v;
                        sq[nt] = fmaf(v, v, sq[nt]);
                    }
                }
            }
        }
    }
    #pragma unroll
    for (int nt = 0; nt < 3; ++nt) {
        float s = ss[nt], q = sq[nt];
        s += __shfl_xor(s, 16); q += __shfl_xor(q, 16);
        s += __shfl_xor(s, 32); q += __shfl_xor(q, 32);
        if (kg == 0) { sS[wv][nt*16 + row] = s; sQ[wv][nt*16 + row] = q; }
    }
    __syncthreads();
    if (tid < 40) {
        float s = sS[0][tid]+sS[1][tid]+sS[2][tid]+sS[3][tid];
        float q = sQ[0][tid]+sQ[1][tid]+sQ[2][tid]+sQ[3][tid];
        atomicAdd(&stats[tid], s);
        atomicAdd(&stats[40 + tid], q);
    }
}

// ---------------- kD: bn1 finalize + out2 = elu(bn1(pooled)) @ w2^T + b2 + bn2 sums ----
__global__ __launch_bounds__(256) void kD(const u16* __restrict__ pooled,
                                          const u16* __restrict__ Wbf2,
                                          const float* __restrict__ b2,
                                          const float* __restrict__ g1,
                                          const float* __restrict__ bb1,
                                          const float* __restrict__ stats,
                                          float* __restrict__ out2,
                                          float* __restrict__ statw) {
    __shared__ float2 scsh[40];
    __shared__ float mrg[2][64][12];
    __shared__ float redS[2][48], redQ[2][48];
    int tid = threadIdx.x;
    if (tid < 40) {
        float mean = stats[tid] / N1F;
        float var  = stats[40 + tid] / N1F - mean * mean;
        float sc   = g1[tid] * rsqrtf(var + 1e-5f);
        scsh[tid] = make_float2(sc, bb1[tid] - mean * sc);
    }
    __syncthreads();
    int wv = tid >> 6, lane = tid & 63, row = lane & 15, kg = lane >> 4;
    int rowgrp = wv >> 1, khalf = wv & 1;
    int mbase = blockIdx.x*32 + rowgrp*16;
    const u16* pr = pooled + (size_t)(mbase + row) * K2;
    f32x4 acc[3];
    #pragma unroll
    for (int i = 0; i < 3; ++i) acc[i] = (f32x4){0.f,0.f,0.f,0.f};

    int ksBeg = khalf ? 39 : 0, ksEnd = khalf ? 79 : 39;
    for (int ks = ksBeg; ks < ksEnd; ++ks) {
        int kbase = ks*32 + kg*8;
        ushort8 cur = *(const ushort8*)&pr[kbase];
        bf16x8 bv0 = *(const bf16x8*)(Wbf2 + (size_t)(row     )*2528 + kbase);
        bf16x8 bv1 = *(const bf16x8*)(Wbf2 + (size_t)(16 + row)*2528 + kbase);
        bf16x8 bv2 = *(const bf16x8*)(Wbf2 + (size_t)(32 + row)*2528 + kbase);
        bf16x8 af;
        bool valid = (ks < 78) | (kg < 3);
        if (valid) {
            #pragma unroll
            for (int j = 0; j < 8; ++j) {
                int k = kbase + j;
                int u = (k * 1639) >> 16;            // k/40 for k<2731
                int o = k - u*40;
                float2 sshf = scsh[o];
                float a = fmaf(bf2f(cur[j]), sshf.x, sshf.y);
                float e = a > 0.f ? a : __expf(a) - 1.f;
                af[j] = (short)f2bf(e);
            }
        } else {
            #pragma unroll
            for (int j = 0; j < 8; ++j) af[j] = 0;
        }
        acc[0] = __builtin_amdgcn_mfma_f32_16x16x32_bf16(af, bv0, acc[0], 0, 0, 0);
        acc[1] = __builtin_amdgcn_mfma_f32_16x16x32_bf16(af, bv1, acc[1], 0, 0, 0);
        acc[2] = __builtin_amdgcn_mfma_f32_16x16x32_bf16(af, bv2, acc[2], 0, 0, 0);
    }

    if (khalf) {
        #pragma unroll
        for (int nf = 0; nf < 3; ++nf)
            #pragma unroll
            for (int r = 0; r < 4; ++r) mrg[rowgrp][lane][nf*4 + r] = acc[nf][r];
    }
    __syncthreads();
    if (!khalf) {
        float sN[3] = {0.f,0.f,0.f}, qN[3] = {0.f,0.f,0.f};
        #pragma unroll
        for (int nf = 0; nf < 3; ++nf) {
            int n = nf*16 + row;
            #pragma unroll
            for (int r = 0; r < 4; ++r) acc[nf][r] += mrg[rowgrp][lane][nf*4 + r];
            if (n < 40) {
                float bias = b2[n];
                #pragma unroll
                for (int r = 0; r < 4; ++r) {
                    float v = acc[nf][r] + bias;
                    out2[(size_t)(mbase + kg*4 + r)*40 + n] = v;
                    sN[nf] += v; qN[nf] += v*v;
                }
            }
        }
        #pragma unroll
        for (int nf = 0; nf < 3; ++nf) {
            float s = sN[nf], q = qN[nf];
            s += __shfl_xor(s, 16); q += __shfl_xor(q, 16);
            s += __shfl_xor(s, 32); q += __shfl_xor(q, 32);
            if (kg == 0) { redS[rowgrp][nf*16 + row] = s; redQ[rowgrp][nf*16 + row] = q; }
        }
    }
    __syncthreads();
    if (tid < 40) {
        atomicAdd(&statw[160 + tid], redS[0][tid] + redS[1][tid]);
        atomicAdd(&statw[200 + tid], redQ[0][tid] + redQ[1][tid]);
    }
}

// ---------------- kF: bn2 finalize + bn2+elu+proj -> z bf16 [512][192] ----------------
__global__ void kF(const float* __restrict__ out2, const float* __restrict__ stats,
                   const float* __restrict__ g2, const float* __restrict__ bb2,
                   const float* __restrict__ pw, const float* __restrict__ pb,
                   u16* __restrict__ zbf) {
    int b = blockIdx.x, t = threadIdx.x;
    __shared__ float sc[40], sh[40], pws[160];
    __shared__ float o2[1840];
    if (t < 40) {
        float mean = stats[160 + t] / N2F;
        float var  = stats[200 + t] / N2F - mean * mean;
        float s    = g2[t] * rsqrtf(var + 1e-5f);
        sc[t] = s;
        sh[t] = bb2[t] - mean * s;
    }
    if (t < 160) pws[t] = pw[t];
    for (int i = t; i < 1840; i += 256) o2[i] = out2[(size_t)b*1840 + i];
    __syncthreads();
    if (t < 192) {
        float accv = 0.f;
        if (t < HID) {
            int w = t >> 2, e = t & 3;
            accv = pb[e];
            for (int o = 0; o < 40; ++o) {
                float a = o2[w*40 + o];
                float act = a * sc[o] + sh[o];
                act = act > 0.f ? act : __expf(act) - 1.f;
                accv = fmaf(act, pws[e*40 + o], accv);
            }
        }
        zbf[(size_t)b*192 + t] = f2bf(accv);
    }
}

// ---------------- kG1: h1 = z @ fc1_w^T + b (MFMA); g = gelu(h1) bf16 ----------------
__global__ __launch_bounds__(256) void kG1(const u16* __restrict__ zbf, const u16* __restrict__ fwbf1,
                                           const float* __restrict__ fb,
                                           float* __restrict__ h1, u16* __restrict__ gbf) {
    int n0 = blockIdx.x * 64, m0 = blockIdx.y * 16;
    int tid = threadIdx.x, wv = tid >> 6, lane = tid & 63, row = lane & 15, kg = lane >> 4;
    const u16* zr = zbf + (size_t)(m0 + row) * 192;
    const u16* wr = fwbf1 + (size_t)(n0 + wv*16 + row) * 192;
    f32x4 acc = (f32x4){0.f,0.f,0.f,0.f};
    #pragma unroll
    for (int ks = 0; ks < 6; ++ks) {
        bf16x8 av = *(const bf16x8*)(zr + ks*32 + kg*8);
        bf16x8 bv = *(const bf16x8*)(wr + ks*32 + kg*8);
        acc = __builtin_amdgcn_mfma_f32_16x16x32_bf16(av, bv, acc, 0, 0, 0);
    }
    int n = n0 + wv*16 + row;
    float bias = fb[n];
    #pragma unroll
    for (int r = 0; r < 4; ++r) {
        int m = m0 + kg*4 + r;
        float v = acc[r] + bias;
        h1[(size_t)m*PROJ + n] = v;
        float ge = 0.5f * v * (1.f + erff(v * 0.70710678118f));
        gbf[(size_t)m*PROJ + n] = f2bf(ge);
    }
}

// ---------------- kG2: h2 = h1 + g @ fc2_w^T + b (MFMA) ----------------
__global__ __launch_bounds__(256) void kG2(const u16* __restrict__ gbf, const u16* __restrict__ fwbf,
                                           const float* __restrict__ fb, const float* __restrict__ h1,
                                           float* __restrict__ h2) {
    int n0 = blockIdx.x * 32, m0 = blockIdx.y * 64;
    int tid = threadIdx.x;
    int wv = tid >> 6, lane = tid & 63, row = lane & 15, kg = lane >> 4;
    const u16* gr = gbf + (size_t)(m0 + wv*16 + row) * PROJ;
    f32x4 acc[2];
    #pragma unroll
    for (int i = 0; i < 2; ++i) acc[i] = (f32x4){0.f,0.f,0.f,0.f};
    for (int ks = 0; ks < 32; ++ks) {
        int kbase = ks*32 + kg*8;
        bf16x8 av  = *(const bf16x8*)(gr + kbase);
        bf16x8 bv0 = *(const bf16x8*)(fwbf + (size_t)(n0      + row)*PROJ + kbase);
        bf16x8 bv1 = *(const bf16x8*)(fwbf + (size_t)(n0 + 16 + row)*PROJ + kbase);
        acc[0] = __builtin_amdgcn_mfma_f32_16x16x32_bf16(av, bv0, acc[0], 0, 0, 0);
        acc[1] = __builtin_amdgcn_mfma_f32_16x16x32_bf16(av, bv1, acc[1], 0, 0, 0);
    }
    int m = m0 + wv*16 + kg*4;
    #pragma unroll
    for (int nf = 0; nf < 2; ++nf) {
        int n = n0 + nf*16 + row;
        float bias = fb[n];
        #pragma unroll
        for (int r = 0; r < 4; ++r)
            h2[(size_t)(m + r)*PROJ + n] = acc[nf][r] + bias + h1[(size_t)(m + r)*PROJ + n];
    }
}

// ---------------- kG3: LayerNorm rows of 1024 ----------------
__global__ __launch_bounds__(256) void kG3(const float* __restrict__ h2, const float* __restrict__ lg,
                                           const float* __restrict__ lb, float* __restrict__ out) {
    int b = blockIdx.x, tid = threadIdx.x;
    float4 v = *(const float4*)&h2[(size_t)b*PROJ + tid*4];
    float s = v.x + v.y + v.z + v.w;
    float q = v.x*v.x + v.y*v.y + v.z*v.z + v.w*v.w;
    __shared__ float ps[4], pq[4], mb[2];
    int wave = tid >> 6, lane = tid & 63;
    #pragma unroll
    for (int d = 32; d >= 1; d >>= 1) { s += __shfl_down(s, d); q += __shfl_down(q, d); }
    if (lane == 0) { ps[wave] = s; pq[wave] = q; }
    __syncthreads();
    if (tid == 0) {
        float S = ps[0]+ps[1]+ps[2]+ps[3], Q = pq[0]+pq[1]+pq[2]+pq[3];
        float mean = S / 1024.f, var = Q / 1024.f - mean*mean;
        mb[0] = mean; mb[1] = rsqrtf(var + 1e-5f);
    }
    __syncthreads();
    float mean = mb[0], inv = mb[1];
    float4 g4 = *(const float4*)&lg[tid*4];
    float4 b4 = *(const float4*)&lb[tid*4];
    float4 o4;
    o4.x = (v.x - mean)*inv*g4.x + b4.x;
    o4.y = (v.y - mean)*inv*g4.y + b4.y;
    o4.z = (v.z - mean)*inv*g4.z + b4.z;
    o4.w = (v.w - mean)*inv*g4.w + b4.w;
    *(float4*)&out[(size_t)b*PROJ + tid*4] = o4;
}

extern "C" void kernel_launch(void* const* d_in, const int* in_sizes, int n_in,
                              void* d_out, int out_size, void* d_ws, size_t ws_size,
                              hipStream_t stream) {
    const float* x       = (const float*)d_in[0];
    const int*   subjects= (const int*)  d_in[1];
    const float* W_subj  = (const float*)d_in[2];
    const float* b_subj  = (const float*)d_in[3];
    const float* conv1_w = (const float*)d_in[4];
    const float* conv1_b = (const float*)d_in[5];
    const float* bn1_g   = (const float*)d_in[6];
    const float* bn1_b   = (const float*)d_in[7];
    const float* conv2_w = (const float*)d_in[8];
    const float* conv2_b = (const float*)d_in[9];
    const float* bn2_g   = (const float*)d_in[10];
    const float* bn2_b   = (const float*)d_in[11];
    const float* proj_w  = (const float*)d_in[12];
    const float* proj_b  = (const float*)d_in[13];
    const float* fc1_w   = (const float*)d_in[14];
    const float* fc1_b   = (const float*)d_in[15];
    const float* fc2_w   = (const float*)d_in[16];
    const float* fc2_b   = (const float*)d_in[17];
    const float* ln_g    = (const float*)d_in[18];
    const float* ln_b    = (const float*)d_in[19];
    float* out = (float*)d_out;

    char* ws = (char*)d_ws;
    u16*   pooled = (u16*)  ws;                      // 118,702,080 B
    float* out2   = (float*)(ws + 118702144);        // 3,768,320 B
    u16*   zbf    = (u16*)  (ws + 122470464);        // 196,608 B
    float* h1     = (float*)(ws + 122667072);        // 2,097,152 B
    float* h2     = (float*)(ws + 124764224);        // 2,097,152 B
    u16*   gbf    = (u16*)  (ws + 126861376);        // 1,048,576 B
    float* stats  = (float*)(ws + 127909952);        // 1,280 B (pad 4096)
    u16*   Wbf    = (u16*)  (ws + 127914048);        // 1,310,720 B
    u16*   Wbf2   = (u16*)  (ws + 129224768);        // 242,688 B
    u16*   fwbf2  = (u16*)  (ws + 129467456);        // 2,097,152 B
    u16*   fwbf1  = (u16*)  (ws + 131564608);        // 393,216 B

    kX  <<<7898, 256, 0, stream>>>(W_subj, conv2_w, fc1_w, fc2_w, Wbf, Wbf2, fwbf1, fwbf2, stats);
    kAB <<<dim3(512, 2), 256, 0, stream>>>(x, subjects, Wbf, b_subj, conv1_w, conv1_b, pooled, stats);
    kD  <<<736, 256, 0, stream>>>(pooled, Wbf2, conv2_b, bn1_g, bn1_b, stats, out2, stats);
    kF  <<<512, 256, 0, stream>>>(out2, stats, bn2_g, bn2_b, proj_w, proj_b, zbf);
    kG1 <<<dim3(16, 32), 256, 0, stream>>>(zbf, fwbf1, fc1_b, h1, gbf);
    kG2 <<<dim3(32, 8), 256, 0, stream>>>(gbf, fwbf2, fc2_b, h1, h2);
    kG3 <<<512, 256, 0, stream>>>(h2, ln_g, ln_b, out);
    (void)in_sizes; (void)n_in; (void)out_size; (void)ws_size;
}

// Round 8
// 261.818 us; speedup vs baseline: 1.1817x; 1.0790x over previous
//
#include <hip/hip_runtime.h>
#include <hip/hip_bf16.h>

#define K2 2520
#define PROJ 1024
#define HID 184
#define N1F (512.f*63.f*46.f)
#define N2F (512.f*46.f)

typedef float f32x4 __attribute__((ext_vector_type(4)));
typedef short bf16x8 __attribute__((ext_vector_type(8)));
typedef unsigned short u16;
typedef unsigned short ushort8 __attribute__((ext_vector_type(8)));
typedef unsigned int u32;
typedef unsigned int u32x4 __attribute__((ext_vector_type(4)));

__device__ __forceinline__ u16 f2bf(float f) {   // RNE fp32 -> bf16 bits
    unsigned u = __builtin_bit_cast(unsigned, f);
    return (u16)((u + 0x7FFFu + ((u >> 16) & 1u)) >> 16);
}
__device__ __forceinline__ float bf2f(u16 h) {
    unsigned u = ((unsigned)h) << 16;
    return __builtin_bit_cast(float, u);
}
__device__ __forceinline__ u32 cvtpk(float lo, float hi) {  // bf16(lo) | bf16(hi)<<16
    u32 r;
    asm("v_cvt_pk_bf16_f32 %0, %1, %2" : "=v"(r) : "v"(lo), "v"(hi));
    return r;
}

// ---------------- kX: merged weight prep + stats zero ----------------
// [0,2560): W_subj -> Wpk fragment-packed [sj][ks][nf][row][kg][8] (65536/subject)
// [2560,3034): conv2_w->Wbf2 [48][2528] (k=c*40+o); [3034,3802): fc1_w->fwbf1 [1024][192];
// [3802,7898): fc2_w->fwbf2 [1024][1024]
__global__ void kX(const float* __restrict__ W, const float* __restrict__ w2,
                   const float* __restrict__ fw1, const float* __restrict__ fw2,
                   u16* __restrict__ Wbf, u16* __restrict__ Wbf2,
                   u16* __restrict__ fwbf1, u16* __restrict__ fwbf2, float* stats) {
    int bid = blockIdx.x, tid = threadIdx.x;
    if (bid == 0 && tid < 320) stats[tid] = 0.f;
    if (bid < 2560) {
        int i = bid*256 + tid;
        int j  = i & 7, kg = (i >> 3) & 3, row = (i >> 5) & 15;
        int nf = (i >> 9) & 15, ks = (i >> 13) & 7, sj = i >> 16;
        int s_ = nf*16 + row, t_ = ks*32 + kg*8 + j;
        float v = (s_ < 250 && t_ < 250) ? W[(size_t)sj*62500 + s_*250 + t_] : 0.f;
        Wbf[i] = f2bf(v);
    } else if (bid < 3034) {
        int i = (bid-2560)*256 + tid;
        int n = i / 2528, k = i - n*2528;
        float v = 0.f;
        if (n < 40 && k < K2) { int c = k/40, o = k - c*40; v = w2[n*K2 + o*63 + c]; }
        Wbf2[i] = f2bf(v);
    } else if (bid < 3802) {
        int i = (bid-3034)*256 + tid;
        int n = i/192, k = i - n*192;
        fwbf1[i] = f2bf(k < HID ? fw1[n*HID + k] : 0.f);
    } else {
        int i = (bid-3802)*256 + tid;
        fwbf2[i] = f2bf(fw2[i]);
    }
}

// ---------------- kAB: LDS-staged subject-matmul (MFMA) + hi/lo-split MFMA conv+pool ----
// grid (512 b, 2 c-halves), block 256. pooled [b][w][k], k = c*40+o. bn1 partial sums.
#define XS(c,s) xs[(c)*258 + (s)]
__global__ __launch_bounds__(256) void kAB(const float* __restrict__ x,
                                           const int* __restrict__ subj,
                                           const u16* __restrict__ Wpk,
                                           const float* __restrict__ bsub,
                                           const float* __restrict__ w1,
                                           const float* __restrict__ b1,
                                           u16* __restrict__ pooled,
                                           float* __restrict__ stats) {
    __shared__ float xs[32*258 + 16];   // staged x (phase1), then x_eeg tile (phase2)
    __shared__ u16 effh[48*32] __attribute__((aligned(16)));
    __shared__ u16 effl[48*32] __attribute__((aligned(16)));
    __shared__ float biasL[256];
    __shared__ float sS[4][48], sQ[4][48];
    int b = blockIdx.x, ch = blockIdx.y;
    int sj = subj[b];
    int tid = threadIdx.x;
    int wv = tid >> 6, lane = tid & 63, row = lane & 15, kg = lane >> 4;

    // ---- phase 0: stage x rows (coalesced float2), bias row, hi/lo eff filter
    {
        int srow = tid >> 3, st8 = tid & 7;
        int cg0 = ch*32 + srow;
        const float* xrow = x + ((size_t)b*63 + (cg0 < 63 ? cg0 : 62))*250;
        #pragma unroll
        for (int q = 0; q < 16; ++q) {
            int c2i = st8 + 8*q;
            if (c2i < 125) {
                float2 v = *(const float2*)&xrow[2*c2i];
                *(float2*)&XS(srow, 2*c2i) = v;
            }
        }
        XS(srow, 250 + st8) = 0.f;             // zero cols [250,258)
        if (tid < 16) xs[32*258 + tid] = 0.f;  // tail pad
    }
    biasL[tid] = (tid < 250) ? bsub[sj*250 + tid] : 0.f;
    for (int i = tid; i < 1536; i += 256) {
        int o = i >> 5, tap = i & 31;
        float e = 0.f;
        if (o < 40 && tap < 21) {
            #pragma unroll
            for (int k = 0; k < 5; ++k) { int u = tap - k; if (u >= 0 && u <= 16) e += w1[o*5+k]; }
            e *= (1.f/17.f);
        }
        u16 h = f2bf(e);
        effh[i] = h;
        effl[i] = f2bf(e - bf2f(h));
    }
    __syncthreads();

    // ---- phase 1: MFMA x_eeg rows (c) x cols (s); wave = (cgrp, nf-half)
    int cgrp = wv & 1, nfh = wv >> 1;
    const u16* Wp = Wpk + (size_t)sj*65536 + ((size_t)row*4 + kg)*8;
    f32x4 acc[8];
    #pragma unroll
    for (int i = 0; i < 8; ++i) acc[i] = (f32x4){0.f,0.f,0.f,0.f};
    #pragma unroll
    for (int ks = 0; ks < 8; ++ks) {
        int tb = ks*32 + kg*8;
        float av[8];
        #pragma unroll
        for (int j = 0; j < 8; ++j) av[j] = XS(cgrp*16 + row, tb + j);
        u32x4 p;
        p[0]=cvtpk(av[0],av[1]); p[1]=cvtpk(av[2],av[3]);
        p[2]=cvtpk(av[4],av[5]); p[3]=cvtpk(av[6],av[7]);
        bf16x8 af = __builtin_bit_cast(bf16x8, p);
        #pragma unroll
        for (int nf2 = 0; nf2 < 8; ++nf2) {
            bf16x8 bv = *(const bf16x8*)(Wp + (size_t)(ks*16 + nfh*8 + nf2)*512);
            acc[nf2] = __builtin_amdgcn_mfma_f32_16x16x32_bf16(af, bv, acc[nf2], 0, 0, 0);
        }
    }
    __syncthreads();    // all phase-1 LDS reads done; overwrite xs with x_eeg
    int cw = cgrp*16 + kg*4;
    #pragma unroll
    for (int nf2 = 0; nf2 < 8; ++nf2) {
        int s = (nfh*8 + nf2)*16 + row;
        float bias = biasL[s];
        #pragma unroll
        for (int r = 0; r < 4; ++r) XS(cw + r, s) = acc[nf2][r] + bias;
    }
    __syncthreads();

    // ---- phase 2: hi/lo MFMA conv+pool
    bf16x8 bvh[3], bvl[3];
    float b1v[3];
    bool ovalid[3];
    #pragma unroll
    for (int nt = 0; nt < 3; ++nt) {
        bvh[nt] = *(const bf16x8*)(effh + (nt*16 + row)*32 + kg*8);
        bvl[nt] = *(const bf16x8*)(effl + (nt*16 + row)*32 + kg*8);
        int o = nt*16 + row;
        ovalid[nt] = o < 40;
        b1v[nt] = ovalid[nt] ? b1[o] : 0.f;
    }
    float ss[3] = {0.f,0.f,0.f}, sq[3] = {0.f,0.f,0.f};
    int climit = ch ? 31 : 32;
    for (int c2 = wv; c2 < climit; c2 += 4) {
        f32x4 acc2[3][3];
        #pragma unroll
        for (int mt = 0; mt < 3; ++mt) {
            int base = c2*258 + 5*(mt*16 + row) + kg*8;
            float av[8];
            #pragma unroll
            for (int j = 0; j < 8; ++j) av[j] = xs[base + j];
            u32x4 ph, pl;
            #pragma unroll
            for (int p = 0; p < 4; ++p) {
                u32 h = cvtpk(av[2*p], av[2*p+1]);
                float h0 = __builtin_bit_cast(float, h << 16);
                float h1 = __builtin_bit_cast(float, h & 0xFFFF0000u);
                ph[p] = h;
                pl[p] = cvtpk(av[2*p] - h0, av[2*p+1] - h1);
            }
            bf16x8 afh = __builtin_bit_cast(bf16x8, ph);
            bf16x8 afl = __builtin_bit_cast(bf16x8, pl);
            #pragma unroll
            for (int nt = 0; nt < 3; ++nt) {
                f32x4 a = (f32x4){b1v[nt], b1v[nt], b1v[nt], b1v[nt]};
                a = __builtin_amdgcn_mfma_f32_16x16x32_bf16(afl, bvh[nt], a, 0, 0, 0);
                a = __builtin_amdgcn_mfma_f32_16x16x32_bf16(afh, bvl[nt], a, 0, 0, 0);
                a = __builtin_amdgcn_mfma_f32_16x16x32_bf16(afh, bvh[nt], a, 0, 0, 0);
                acc2[mt][nt] = a;
            }
        }
        u16* prow = pooled + (size_t)b*46*K2 + (ch*32 + c2)*40;
        #pragma unroll
        for (int mt = 0; mt < 3; ++mt) {
            #pragma unroll
            for (int nt = 0; nt < 3; ++nt) {
                if (!ovalid[nt]) continue;
                int o = nt*16 + row;
                #pragma unroll
                for (int r = 0; r < 4; ++r) {
                    int w = mt*16 + kg*4 + r;
                    if (mt < 2 || w < 46) {
                        float v = acc2[mt][nt][r];
                        prow[(size_t)w*K2 + o] = f2bf(v);
                        ss[nt] += v;
                        sq[nt] = fmaf(v, v, sq[nt]);
                    }
                }
            }
        }
    }
    #pragma unroll
    for (int nt = 0; nt < 3; ++nt) {
        float s = ss[nt], q = sq[nt];
        s += __shfl_xor(s, 16); q += __shfl_xor(q, 16);
        s += __shfl_xor(s, 32); q += __shfl_xor(q, 32);
        if (kg == 0) { sS[wv][nt*16 + row] = s; sQ[wv][nt*16 + row] = q; }
    }
    __syncthreads();
    if (tid < 40) {
        float s = sS[0][tid]+sS[1][tid]+sS[2][tid]+sS[3][tid];
        float q = sQ[0][tid]+sQ[1][tid]+sQ[2][tid]+sQ[3][tid];
        atomicAdd(&stats[tid], s);
        atomicAdd(&stats[40 + tid], q);
    }
}

// ---------------- kD: bn1 finalize + out2 = elu(bn1(pooled)) @ w2^T + b2 + bn2 sums ----
__global__ __launch_bounds__(256) void kD(const u16* __restrict__ pooled,
                                          const u16* __restrict__ Wbf2,
                                          const float* __restrict__ b2,
                                          const float* __restrict__ g1,
                                          const float* __restrict__ bb1,
                                          const float* __restrict__ stats,
                                          float* __restrict__ out2,
                                          float* __restrict__ statw) {
    __shared__ float2 scsh[40];
    __shared__ float mrg[2][64][12];
    __shared__ float redS[2][48], redQ[2][48];
    int tid = threadIdx.x;
    if (tid < 40) {
        float mean = stats[tid] / N1F;
        float var  = stats[40 + tid] / N1F - mean * mean;
        float sc   = g1[tid] * rsqrtf(var + 1e-5f);
        scsh[tid] = make_float2(sc, bb1[tid] - mean * sc);
    }
    __syncthreads();
    int wv = tid >> 6, lane = tid & 63, row = lane & 15, kg = lane >> 4;
    int rowgrp = wv >> 1, khalf = wv & 1;
    int mbase = blockIdx.x*32 + rowgrp*16;
    const u16* pr = pooled + (size_t)(mbase + row) * K2;
    f32x4 acc[3];
    #pragma unroll
    for (int i = 0; i < 3; ++i) acc[i] = (f32x4){0.f,0.f,0.f,0.f};

    int ksBeg = khalf ? 39 : 0, ksEnd = khalf ? 79 : 39;
    for (int ks = ksBeg; ks < ksEnd; ++ks) {
        int kbase = ks*32 + kg*8;
        ushort8 cur = *(const ushort8*)&pr[kbase];
        bf16x8 bv0 = *(const bf16x8*)(Wbf2 + (size_t)(row     )*2528 + kbase);
        bf16x8 bv1 = *(const bf16x8*)(Wbf2 + (size_t)(16 + row)*2528 + kbase);
        bf16x8 bv2 = *(const bf16x8*)(Wbf2 + (size_t)(32 + row)*2528 + kbase);
        bf16x8 af;
        bool valid = (ks < 78) | (kg < 3);
        if (valid) {
            // o = (kbase+j)%40 = o0+j, o0 = 8*((4ks+kg)%5) (no wrap: o0<=32, j<=7)
            int m5 = 4*ks + kg;
            int o0 = (m5 - 5*((m5*52429) >> 18)) * 8;
            #pragma unroll
            for (int j = 0; j < 8; ++j) {
                float2 sshf = scsh[o0 + j];
                float a = fmaf(bf2f(cur[j]), sshf.x, sshf.y);
                float e = a > 0.f ? a : __expf(a) - 1.f;
                af[j] = (short)f2bf(e);
            }
        } else {
            #pragma unroll
            for (int j = 0; j < 8; ++j) af[j] = 0;
        }
        acc[0] = __builtin_amdgcn_mfma_f32_16x16x32_bf16(af, bv0, acc[0], 0, 0, 0);
        acc[1] = __builtin_amdgcn_mfma_f32_16x16x32_bf16(af, bv1, acc[1], 0, 0, 0);
        acc[2] = __builtin_amdgcn_mfma_f32_16x16x32_bf16(af, bv2, acc[2], 0, 0, 0);
    }

    if (khalf) {
        #pragma unroll
        for (int nf = 0; nf < 3; ++nf)
            #pragma unroll
            for (int r = 0; r < 4; ++r) mrg[rowgrp][lane][nf*4 + r] = acc[nf][r];
    }
    __syncthreads();
    if (!khalf) {
        float sN[3] = {0.f,0.f,0.f}, qN[3] = {0.f,0.f,0.f};
        #pragma unroll
        for (int nf = 0; nf < 3; ++nf) {
            int n = nf*16 + row;
            #pragma unroll
            for (int r = 0; r < 4; ++r) acc[nf][r] += mrg[rowgrp][lane][nf*4 + r];
            if (n < 40) {
                float bias = b2[n];
                #pragma unroll
                for (int r = 0; r < 4; ++r) {
                    float v = acc[nf][r] + bias;
                    out2[(size_t)(mbase + kg*4 + r)*40 + n] = v;
                    sN[nf] += v; qN[nf] += v*v;
                }
            }
        }
        #pragma unroll
        for (int nf = 0; nf < 3; ++nf) {
            float s = sN[nf], q = qN[nf];
            s += __shfl_xor(s, 16); q += __shfl_xor(q, 16);
            s += __shfl_xor(s, 32); q += __shfl_xor(q, 32);
            if (kg == 0) { redS[rowgrp][nf*16 + row] = s; redQ[rowgrp][nf*16 + row] = q; }
        }
    }
    __syncthreads();
    if (tid < 40) {
        atomicAdd(&statw[160 + tid], redS[0][tid] + redS[1][tid]);
        atomicAdd(&statw[200 + tid], redQ[0][tid] + redQ[1][tid]);
    }
}

// ---------------- kF: bn2 finalize + bn2+elu+proj -> z bf16 [512][192] ----------------
__global__ void kF(const float* __restrict__ out2, const float* __restrict__ stats,
                   const float* __restrict__ g2, const float* __restrict__ bb2,
                   const float* __restrict__ pw, const float* __restrict__ pb,
                   u16* __restrict__ zbf) {
    int b = blockIdx.x, t = threadIdx.x;
    __shared__ float sc[40], sh[40], pws[160];
    __shared__ float o2[1840];
    if (t < 40) {
        float mean = stats[160 + t] / N2F;
        float var  = stats[200 + t] / N2F - mean * mean;
        float s    = g2[t] * rsqrtf(var + 1e-5f);
        sc[t] = s;
        sh[t] = bb2[t] - mean * s;
    }
    if (t < 160) pws[t] = pw[t];
    for (int i = t; i < 1840; i += 256) o2[i] = out2[(size_t)b*1840 + i];
    __syncthreads();
    if (t < 192) {
        float accv = 0.f;
        if (t < HID) {
            int w = t >> 2, e = t & 3;
            accv = pb[e];
            for (int o = 0; o < 40; ++o) {
                float a = o2[w*40 + o];
                float act = a * sc[o] + sh[o];
                act = act > 0.f ? act : __expf(act) - 1.f;
                accv = fmaf(act, pws[e*40 + o], accv);
            }
        }
        zbf[(size_t)b*192 + t] = f2bf(accv);
    }
}

// ---------------- kG1: h1 = z @ fc1_w^T + b (MFMA); g = gelu(h1) bf16 ----------------
__global__ __launch_bounds__(256) void kG1(const u16* __restrict__ zbf, const u16* __restrict__ fwbf1,
                                           const float* __restrict__ fb,
                                           float* __restrict__ h1, u16* __restrict__ gbf) {
    int n0 = blockIdx.x * 64, m0 = blockIdx.y * 16;
    int tid = threadIdx.x, wv = tid >> 6, lane = tid & 63, row = lane & 15, kg = lane >> 4;
    const u16* zr = zbf + (size_t)(m0 + row) * 192;
    const u16* wr = fwbf1 + (size_t)(n0 + wv*16 + row) * 192;
    f32x4 acc = (f32x4){0.f,0.f,0.f,0.f};
    #pragma unroll
    for (int ks = 0; ks < 6; ++ks) {
        bf16x8 av = *(const bf16x8*)(zr + ks*32 + kg*8);
        bf16x8 bv = *(const bf16x8*)(wr + ks*32 + kg*8);
        acc = __builtin_amdgcn_mfma_f32_16x16x32_bf16(av, bv, acc, 0, 0, 0);
    }
    int n = n0 + wv*16 + row;
    float bias = fb[n];
    #pragma unroll
    for (int r = 0; r < 4; ++r) {
        int m = m0 + kg*4 + r;
        float v = acc[r] + bias;
        h1[(size_t)m*PROJ + n] = v;
        float ge = 0.5f * v * (1.f + erff(v * 0.70710678118f));
        gbf[(size_t)m*PROJ + n] = f2bf(ge);
    }
}

// ---------------- kG2: h2 = h1 + g @ fc2_w^T + b (MFMA) ----------------
__global__ __launch_bounds__(256) void kG2(const u16* __restrict__ gbf, const u16* __restrict__ fwbf,
                                           const float* __restrict__ fb, const float* __restrict__ h1,
                                           float* __restrict__ h2) {
    int n0 = blockIdx.x * 32, m0 = blockIdx.y * 64;
    int tid = threadIdx.x;
    int wv = tid >> 6, lane = tid & 63, row = lane & 15, kg = lane >> 4;
    const u16* gr = gbf + (size_t)(m0 + wv*16 + row) * PROJ;
    f32x4 acc[2];
    #pragma unroll
    for (int i = 0; i < 2; ++i) acc[i] = (f32x4){0.f,0.f,0.f,0.f};
    for (int ks = 0; ks < 32; ++ks) {
        int kbase = ks*32 + kg*8;
        bf16x8 av  = *(const bf16x8*)(gr + kbase);
        bf16x8 bv0 = *(const bf16x8*)(fwbf + (size_t)(n0      + row)*PROJ + kbase);
        bf16x8 bv1 = *(const bf16x8*)(fwbf + (size_t)(n0 + 16 + row)*PROJ + kbase);
        acc[0] = __builtin_amdgcn_mfma_f32_16x16x32_bf16(av, bv0, acc[0], 0, 0, 0);
        acc[1] = __builtin_amdgcn_mfma_f32_16x16x32_bf16(av, bv1, acc[1], 0, 0, 0);
    }
    int m = m0 + wv*16 + kg*4;
    #pragma unroll
    for (int nf = 0; nf < 2; ++nf) {
        int n = n0 + nf*16 + row;
        float bias = fb[n];
        #pragma unroll
        for (int r = 0; r < 4; ++r)
            h2[(size_t)(m + r)*PROJ + n] = acc[nf][r] + bias + h1[(size_t)(m + r)*PROJ + n];
    }
}

// ---------------- kG3: LayerNorm rows of 1024 ----------------
__global__ __launch_bounds__(256) void kG3(const float* __restrict__ h2, const float* __restrict__ lg,
                                           const float* __restrict__ lb, float* __restrict__ out) {
    int b = blockIdx.x, tid = threadIdx.x;
    float4 v = *(const float4*)&h2[(size_t)b*PROJ + tid*4];
    float s = v.x + v.y + v.z + v.w;
    float q = v.x*v.x + v.y*v.y + v.z*v.z + v.w*v.w;
    __shared__ float ps[4], pq[4], mb[2];
    int wave = tid >> 6, lane = tid & 63;
    #pragma unroll
    for (int d = 32; d >= 1; d >>= 1) { s += __shfl_down(s, d); q += __shfl_down(q, d); }
    if (lane == 0) { ps[wave] = s; pq[wave] = q; }
    __syncthreads();
    if (tid == 0) {
        float S = ps[0]+ps[1]+ps[2]+ps[3], Q = pq[0]+pq[1]+pq[2]+pq[3];
        float mean = S / 1024.f, var = Q / 1024.f - mean*mean;
        mb[0] = mean; mb[1] = rsqrtf(var + 1e-5f);
    }
    __syncthreads();
    float mean = mb[0], inv = mb[1];
    float4 g4 = *(const float4*)&lg[tid*4];
    float4 b4 = *(const float4*)&lb[tid*4];
    float4 o4;
    o4.x = (v.x - mean)*inv*g4.x + b4.x;
    o4.y = (v.y - mean)*inv*g4.y + b4.y;
    o4.z = (v.z - mean)*inv*g4.z + b4.z;
    o4.w = (v.w - mean)*inv*g4.w + b4.w;
    *(float4*)&out[(size_t)b*PROJ + tid*4] = o4;
}

extern "C" void kernel_launch(void* const* d_in, const int* in_sizes, int n_in,
                              void* d_out, int out_size, void* d_ws, size_t ws_size,
                              hipStream_t stream) {
    const float* x       = (const float*)d_in[0];
    const int*   subjects= (const int*)  d_in[1];
    const float* W_subj  = (const float*)d_in[2];
    const float* b_subj  = (const float*)d_in[3];
    const float* conv1_w = (const float*)d_in[4];
    const float* conv1_b = (const float*)d_in[5];
    const float* bn1_g   = (const float*)d_in[6];
    const float* bn1_b   = (const float*)d_in[7];
    const float* conv2_w = (const float*)d_in[8];
    const float* conv2_b = (const float*)d_in[9];
    const float* bn2_g   = (const float*)d_in[10];
    const float* bn2_b   = (const float*)d_in[11];
    const float* proj_w  = (const float*)d_in[12];
    const float* proj_b  = (const float*)d_in[13];
    const float* fc1_w   = (const float*)d_in[14];
    const float* fc1_b   = (const float*)d_in[15];
    const float* fc2_w   = (const float*)d_in[16];
    const float* fc2_b   = (const float*)d_in[17];
    const float* ln_g    = (const float*)d_in[18];
    const float* ln_b    = (const float*)d_in[19];
    float* out = (float*)d_out;

    char* ws = (char*)d_ws;
    u16*   pooled = (u16*)  ws;                      // 118,702,080 B
    float* out2   = (float*)(ws + 118702144);        // 3,768,320 B
    u16*   zbf    = (u16*)  (ws + 122470464);        // 196,608 B
    float* h1     = (float*)(ws + 122667072);        // 2,097,152 B
    float* h2     = (float*)(ws + 124764224);        // 2,097,152 B
    u16*   gbf    = (u16*)  (ws + 126861376);        // 1,048,576 B
    float* stats  = (float*)(ws + 127909952);        // 1,280 B (pad 4096)
    u16*   Wbf    = (u16*)  (ws + 127914048);        // 1,310,720 B
    u16*   Wbf2   = (u16*)  (ws + 129224768);        // 242,688 B
    u16*   fwbf2  = (u16*)  (ws + 129467456);        // 2,097,152 B
    u16*   fwbf1  = (u16*)  (ws + 131564608);        // 393,216 B

    kX  <<<7898, 256, 0, stream>>>(W_subj, conv2_w, fc1_w, fc2_w, Wbf, Wbf2, fwbf1, fwbf2, stats);
    kAB <<<dim3(512, 2), 256, 0, stream>>>(x, subjects, Wbf, b_subj, conv1_w, conv1_b, pooled, stats);
    kD  <<<736, 256, 0, stream>>>(pooled, Wbf2, conv2_b, bn1_g, bn1_b, stats, out2, stats);
    kF  <<<512, 256, 0, stream>>>(out2, stats, bn2_g, bn2_b, proj_w, proj_b, zbf);
    kG1 <<<dim3(16, 32), 256, 0, stream>>>(zbf, fwbf1, fc1_b, h1, gbf);
    kG2 <<<dim3(32, 8), 256, 0, stream>>>(gbf, fwbf2, fc2_b, h1, h2);
    kG3 <<<512, 256, 0, stream>>>(h2, ln_g, ln_b, out);
    (void)in_sizes; (void)n_in; (void)out_size; (void)ws_size;
}

// Round 9
// 253.996 us; speedup vs baseline: 1.2181x; 1.0308x over previous
//
#include <hip/hip_runtime.h>
#include <hip/hip_bf16.h>

#define K2 2520
#define PROJ 1024
#define HID 184
#define N1F (512.f*63.f*46.f)
#define N2F (512.f*46.f)

typedef float f32x4 __attribute__((ext_vector_type(4)));
typedef short bf16x8 __attribute__((ext_vector_type(8)));
typedef unsigned short u16;
typedef unsigned short ushort8 __attribute__((ext_vector_type(8)));
typedef unsigned int u32;
typedef unsigned int u32x2 __attribute__((ext_vector_type(2)));
typedef unsigned int u32x4 __attribute__((ext_vector_type(4)));

__device__ __forceinline__ u16 f2bf(float f) {   // RNE fp32 -> bf16 bits
    unsigned u = __builtin_bit_cast(unsigned, f);
    return (u16)((u + 0x7FFFu + ((u >> 16) & 1u)) >> 16);
}
__device__ __forceinline__ float bf2f(u16 h) {
    unsigned u = ((unsigned)h) << 16;
    return __builtin_bit_cast(float, u);
}
__device__ __forceinline__ u32 cvtpk(float lo, float hi) {  // bf16(lo) | bf16(hi)<<16
    u32 r;
    asm("v_cvt_pk_bf16_f32 %0, %1, %2" : "=v"(r) : "v"(lo), "v"(hi));
    return r;
}

// ---------------- kX: merged weight prep + stats zero ----------------
// [0,2560): W_subj -> Wpk fragment-packed [sj][ks][nf][row][kg][8] (65536/subject)
// [2560,3034): conv2_w->Wbf2 [48][2528] (k=c*40+o); [3034,3802): fc1_w->fwbf1 [1024][192];
// [3802,7898): fc2_w->fwbf2 [1024][1024]
__global__ void kX(const float* __restrict__ W, const float* __restrict__ w2,
                   const float* __restrict__ fw1, const float* __restrict__ fw2,
                   u16* __restrict__ Wbf, u16* __restrict__ Wbf2,
                   u16* __restrict__ fwbf1, u16* __restrict__ fwbf2, float* stats) {
    int bid = blockIdx.x, tid = threadIdx.x;
    if (bid == 0 && tid < 320) stats[tid] = 0.f;
    if (bid < 2560) {
        int i = bid*256 + tid;
        int j  = i & 7, kg = (i >> 3) & 3, row = (i >> 5) & 15;
        int nf = (i >> 9) & 15, ks = (i >> 13) & 7, sj = i >> 16;
        int s_ = nf*16 + row, t_ = ks*32 + kg*8 + j;
        float v = (s_ < 250 && t_ < 250) ? W[(size_t)sj*62500 + s_*250 + t_] : 0.f;
        Wbf[i] = f2bf(v);
    } else if (bid < 3034) {
        int i = (bid-2560)*256 + tid;
        int n = i / 2528, k = i - n*2528;
        float v = 0.f;
        if (n < 40 && k < K2) { int c = k/40, o = k - c*40; v = w2[n*K2 + o*63 + c]; }
        Wbf2[i] = f2bf(v);
    } else if (bid < 3802) {
        int i = (bid-3034)*256 + tid;
        int n = i/192, k = i - n*192;
        fwbf1[i] = f2bf(k < HID ? fw1[n*HID + k] : 0.f);
    } else {
        int i = (bid-3802)*256 + tid;
        fwbf2[i] = f2bf(fw2[i]);
    }
}

// ---------------- kAB: LDS-staged subject-matmul (MFMA) + hi/lo-split MFMA conv+pool ----
// grid (512 b, 2 c-halves), block 256. pooled layout [b][c][w][o] (per-(b,c) slab of
// 46x40 u16 contiguous). Phase 2 MFMA operands swapped (A=eff rows o, B=x rows w) so
// each lane holds 4 consecutive o -> one 8B u32x2 store (4x fewer store instrs).
#define XS(c,s) xs[(c)*258 + (s)]
__global__ __launch_bounds__(256) void kAB(const float* __restrict__ x,
                                           const int* __restrict__ subj,
                                           const u16* __restrict__ Wpk,
                                           const float* __restrict__ bsub,
                                           const float* __restrict__ w1,
                                           const float* __restrict__ b1,
                                           u16* __restrict__ pooled,
                                           float* __restrict__ stats) {
    __shared__ float xs[32*258 + 16];   // staged x (phase1), then x_eeg tile (phase2)
    __shared__ u16 effh[48*32] __attribute__((aligned(16)));
    __shared__ u16 effl[48*32] __attribute__((aligned(16)));
    __shared__ float biasL[256];
    __shared__ float sS[4][48], sQ[4][48];
    int b = blockIdx.x, ch = blockIdx.y;
    int sj = subj[b];
    int tid = threadIdx.x;
    int wv = tid >> 6, lane = tid & 63, row = lane & 15, kg = lane >> 4;

    // ---- phase 0: stage x rows (coalesced float2), bias row, hi/lo eff filter
    {
        int srow = tid >> 3, st8 = tid & 7;
        int cg0 = ch*32 + srow;
        const float* xrow = x + ((size_t)b*63 + (cg0 < 63 ? cg0 : 62))*250;
        #pragma unroll
        for (int q = 0; q < 16; ++q) {
            int c2i = st8 + 8*q;
            if (c2i < 125) {
                float2 v = *(const float2*)&xrow[2*c2i];
                *(float2*)&XS(srow, 2*c2i) = v;
            }
        }
        XS(srow, 250 + st8) = 0.f;             // zero cols [250,258)
        if (tid < 16) xs[32*258 + tid] = 0.f;  // tail pad
    }
    biasL[tid] = (tid < 250) ? bsub[sj*250 + tid] : 0.f;
    for (int i = tid; i < 1536; i += 256) {
        int o = i >> 5, tap = i & 31;
        float e = 0.f;
        if (o < 40 && tap < 21) {
            #pragma unroll
            for (int k = 0; k < 5; ++k) { int u = tap - k; if (u >= 0 && u <= 16) e += w1[o*5+k]; }
            e *= (1.f/17.f);
        }
        u16 h = f2bf(e);
        effh[i] = h;
        effl[i] = f2bf(e - bf2f(h));
    }
    __syncthreads();

    // ---- phase 1: MFMA x_eeg rows (c) x cols (s); wave = (cgrp, nf-half)
    int cgrp = wv & 1, nfh = wv >> 1;
    const u16* Wp = Wpk + (size_t)sj*65536 + ((size_t)row*4 + kg)*8;
    f32x4 acc[8];
    #pragma unroll
    for (int i = 0; i < 8; ++i) acc[i] = (f32x4){0.f,0.f,0.f,0.f};
    #pragma unroll
    for (int ks = 0; ks < 8; ++ks) {
        int tb = ks*32 + kg*8;
        float av[8];
        #pragma unroll
        for (int j = 0; j < 8; ++j) av[j] = XS(cgrp*16 + row, tb + j);
        u32x4 p;
        p[0]=cvtpk(av[0],av[1]); p[1]=cvtpk(av[2],av[3]);
        p[2]=cvtpk(av[4],av[5]); p[3]=cvtpk(av[6],av[7]);
        bf16x8 af = __builtin_bit_cast(bf16x8, p);
        #pragma unroll
        for (int nf2 = 0; nf2 < 8; ++nf2) {
            bf16x8 bv = *(const bf16x8*)(Wp + (size_t)(ks*16 + nfh*8 + nf2)*512);
            acc[nf2] = __builtin_amdgcn_mfma_f32_16x16x32_bf16(af, bv, acc[nf2], 0, 0, 0);
        }
    }
    __syncthreads();    // all phase-1 LDS reads done; overwrite xs with x_eeg
    int cw = cgrp*16 + kg*4;
    #pragma unroll
    for (int nf2 = 0; nf2 < 8; ++nf2) {
        int s = (nfh*8 + nf2)*16 + row;
        float bias = biasL[s];
        #pragma unroll
        for (int r = 0; r < 4; ++r) XS(cw + r, s) = acc[nf2][r] + bias;
    }
    __syncthreads();

    // ---- phase 2: hi/lo MFMA conv+pool, swapped operands: D[o=nt*16+kg*4+r][w=mt*16+row]
    bf16x8 avh[3], avl[3];
    f32x4 cin3[3];
    #pragma unroll
    for (int nt = 0; nt < 3; ++nt) {
        avh[nt] = *(const bf16x8*)(effh + (nt*16 + row)*32 + kg*8);
        avl[nt] = *(const bf16x8*)(effl + (nt*16 + row)*32 + kg*8);
        int ob = nt*16 + kg*4;
        if (ob < 40) cin3[nt] = *(const f32x4*)&b1[ob];
        else         cin3[nt] = (f32x4){0.f,0.f,0.f,0.f};
    }
    float ss[3][4] = {}, sq[3][4] = {};
    int climit = ch ? 31 : 32;
    for (int c2 = wv; c2 < climit; c2 += 4) {
        u16* prow = pooled + (size_t)b*115920 + (size_t)(ch*32 + c2)*1840;
        #pragma unroll
        for (int mt = 0; mt < 3; ++mt) {
            int base = c2*258 + 5*(mt*16 + row) + kg*8;
            float av[8];
            #pragma unroll
            for (int j = 0; j < 8; ++j) av[j] = xs[base + j];
            u32x4 ph, pl;
            #pragma unroll
            for (int p = 0; p < 4; ++p) {
                u32 h = cvtpk(av[2*p], av[2*p+1]);
                float h0 = __builtin_bit_cast(float, h << 16);
                float h1 = __builtin_bit_cast(float, h & 0xFFFF0000u);
                ph[p] = h;
                pl[p] = cvtpk(av[2*p] - h0, av[2*p+1] - h1);
            }
            bf16x8 bfh = __builtin_bit_cast(bf16x8, ph);
            bf16x8 bfl = __builtin_bit_cast(bf16x8, pl);
            int w = mt*16 + row;
            bool wvalid = w < 46;
            #pragma unroll
            for (int nt = 0; nt < 3; ++nt) {
                f32x4 a = cin3[nt];
                a = __builtin_amdgcn_mfma_f32_16x16x32_bf16(avh[nt], bfl, a, 0, 0, 0);
                a = __builtin_amdgcn_mfma_f32_16x16x32_bf16(avl[nt], bfh, a, 0, 0, 0);
                a = __builtin_amdgcn_mfma_f32_16x16x32_bf16(avh[nt], bfh, a, 0, 0, 0);
                int ob = nt*16 + kg*4;
                if (wvalid && ob < 40) {
                    u32x2 pk;
                    pk[0] = cvtpk(a[0], a[1]);
                    pk[1] = cvtpk(a[2], a[3]);
                    *(u32x2*)&prow[(size_t)w*40 + ob] = pk;
                    #pragma unroll
                    for (int r = 0; r < 4; ++r) {
                        ss[nt][r] += a[r];
                        sq[nt][r] = fmaf(a[r], a[r], sq[nt][r]);
                    }
                }
            }
        }
    }
    // reduce over w (lane&15) then across waves
    #pragma unroll
    for (int nt = 0; nt < 3; ++nt) {
        #pragma unroll
        for (int r = 0; r < 4; ++r) {
            float s = ss[nt][r], q = sq[nt][r];
            s += __shfl_xor(s, 1); q += __shfl_xor(q, 1);
            s += __shfl_xor(s, 2); q += __shfl_xor(q, 2);
            s += __shfl_xor(s, 4); q += __shfl_xor(q, 4);
            s += __shfl_xor(s, 8); q += __shfl_xor(q, 8);
            if (row == 0) {
                int ob = nt*16 + kg*4;
                if (ob < 40) { sS[wv][ob + r] = s; sQ[wv][ob + r] = q; }
            }
        }
    }
    __syncthreads();
    if (tid < 40) {
        float s = sS[0][tid]+sS[1][tid]+sS[2][tid]+sS[3][tid];
        float q = sQ[0][tid]+sQ[1][tid]+sQ[2][tid]+sQ[3][tid];
        atomicAdd(&stats[tid], s);
        atomicAdd(&stats[40 + tid], q);
    }
}

// ---------------- kD: bn1 finalize + out2 = elu(bn1(pooled)) @ w2^T + b2 + bn2 sums ----
// pooled is [b][c][w][o]; lane row m -> (b,w); k-offset = c*1840 + o5*8 (16B loads, no wrap).
__global__ __launch_bounds__(256) void kD(const u16* __restrict__ pooled,
                                          const u16* __restrict__ Wbf2,
                                          const float* __restrict__ b2,
                                          const float* __restrict__ g1,
                                          const float* __restrict__ bb1,
                                          const float* __restrict__ stats,
                                          float* __restrict__ out2,
                                          float* __restrict__ statw) {
    __shared__ float2 scsh[40];
    __shared__ float mrg[2][64][12];
    __shared__ float redS[2][48], redQ[2][48];
    int tid = threadIdx.x;
    if (tid < 40) {
        float mean = stats[tid] / N1F;
        float var  = stats[40 + tid] / N1F - mean * mean;
        float sc   = g1[tid] * rsqrtf(var + 1e-5f);
        scsh[tid] = make_float2(sc, bb1[tid] - mean * sc);
    }
    __syncthreads();
    int wv = tid >> 6, lane = tid & 63, row = lane & 15, kg = lane >> 4;
    int rowgrp = wv >> 1, khalf = wv & 1;
    int mbase = blockIdx.x*32 + rowgrp*16;
    int m = mbase + row;
    int bb = m / 46, ww = m - bb*46;
    const u16* prl = pooled + (size_t)bb*115920 + (size_t)ww*40;
    f32x4 acc[3];
    #pragma unroll
    for (int i = 0; i < 3; ++i) acc[i] = (f32x4){0.f,0.f,0.f,0.f};

    int ksBeg = khalf ? 39 : 0, ksEnd = khalf ? 79 : 39;
    int t0 = 4*ksBeg + kg;
    int ci = (t0*52429) >> 18, o5i = t0 - 5*ci;
    ushort8 cur = *(const ushort8*)(prl + ci*1840 + o5i*8);
    for (int ks = ksBeg; ks < ksEnd; ++ks) {
        ushort8 nxt = cur;
        if (ks + 1 < ksEnd) {
            int tn = 4*(ks+1) + kg;
            int cn = (tn*52429) >> 18, o5n = tn - 5*cn;
            nxt = *(const ushort8*)(prl + cn*1840 + o5n*8);
        }
        int kbase = ks*32 + kg*8;
        bf16x8 bv0 = *(const bf16x8*)(Wbf2 + (size_t)(row     )*2528 + kbase);
        bf16x8 bv1 = *(const bf16x8*)(Wbf2 + (size_t)(16 + row)*2528 + kbase);
        bf16x8 bv2 = *(const bf16x8*)(Wbf2 + (size_t)(32 + row)*2528 + kbase);
        bf16x8 af;
        bool valid = (ks < 78) | (kg < 3);
        if (valid) {
            int tt = 4*ks + kg;
            int cc = (tt*52429) >> 18;
            int o0 = (tt - 5*cc) * 8;
            #pragma unroll
            for (int j = 0; j < 8; ++j) {
                float2 sshf = scsh[o0 + j];
                float a = fmaf(bf2f(cur[j]), sshf.x, sshf.y);
                float e = a > 0.f ? a : __expf(a) - 1.f;
                af[j] = (short)f2bf(e);
            }
        } else {
            #pragma unroll
            for (int j = 0; j < 8; ++j) af[j] = 0;
        }
        acc[0] = __builtin_amdgcn_mfma_f32_16x16x32_bf16(af, bv0, acc[0], 0, 0, 0);
        acc[1] = __builtin_amdgcn_mfma_f32_16x16x32_bf16(af, bv1, acc[1], 0, 0, 0);
        acc[2] = __builtin_amdgcn_mfma_f32_16x16x32_bf16(af, bv2, acc[2], 0, 0, 0);
        cur = nxt;
    }

    if (khalf) {
        #pragma unroll
        for (int nf = 0; nf < 3; ++nf)
            #pragma unroll
            for (int r = 0; r < 4; ++r) mrg[rowgrp][lane][nf*4 + r] = acc[nf][r];
    }
    __syncthreads();
    if (!khalf) {
        float sN[3] = {0.f,0.f,0.f}, qN[3] = {0.f,0.f,0.f};
        #pragma unroll
        for (int nf = 0; nf < 3; ++nf) {
            int n = nf*16 + row;
            #pragma unroll
            for (int r = 0; r < 4; ++r) acc[nf][r] += mrg[rowgrp][lane][nf*4 + r];
            if (n < 40) {
                float bias = b2[n];
                #pragma unroll
                for (int r = 0; r < 4; ++r) {
                    float v = acc[nf][r] + bias;
                    out2[(size_t)(mbase + kg*4 + r)*40 + n] = v;
                    sN[nf] += v; qN[nf] += v*v;
                }
            }
        }
        #pragma unroll
        for (int nf = 0; nf < 3; ++nf) {
            float s = sN[nf], q = qN[nf];
            s += __shfl_xor(s, 16); q += __shfl_xor(q, 16);
            s += __shfl_xor(s, 32); q += __shfl_xor(q, 32);
            if (kg == 0) { redS[rowgrp][nf*16 + row] = s; redQ[rowgrp][nf*16 + row] = q; }
        }
    }
    __syncthreads();
    if (tid < 40) {
        atomicAdd(&statw[160 + tid], redS[0][tid] + redS[1][tid]);
        atomicAdd(&statw[200 + tid], redQ[0][tid] + redQ[1][tid]);
    }
}

// ---------------- kF: bn2 finalize + bn2+elu+proj -> z bf16 [512][192] ----------------
__global__ void kF(const float* __restrict__ out2, const float* __restrict__ stats,
                   const float* __restrict__ g2, const float* __restrict__ bb2,
                   const float* __restrict__ pw, const float* __restrict__ pb,
                   u16* __restrict__ zbf) {
    int b = blockIdx.x, t = threadIdx.x;
    __shared__ float sc[40], sh[40], pws[160];
    __shared__ float o2[1840];
    if (t < 40) {
        float mean = stats[160 + t] / N2F;
        float var  = stats[200 + t] / N2F - mean * mean;
        float s    = g2[t] * rsqrtf(var + 1e-5f);
        sc[t] = s;
        sh[t] = bb2[t] - mean * s;
    }
    if (t < 160) pws[t] = pw[t];
    for (int i = t; i < 1840; i += 256) o2[i] = out2[(size_t)b*1840 + i];
    __syncthreads();
    if (t < 192) {
        float accv = 0.f;
        if (t < HID) {
            int w = t >> 2, e = t & 3;
            accv = pb[e];
            for (int o = 0; o < 40; ++o) {
                float a = o2[w*40 + o];
                float act = a * sc[o] + sh[o];
                act = act > 0.f ? act : __expf(act) - 1.f;
                accv = fmaf(act, pws[e*40 + o], accv);
            }
        }
        zbf[(size_t)b*192 + t] = f2bf(accv);
    }
}

// ---------------- kG1: h1 = z @ fc1_w^T + b (MFMA); g = gelu(h1) bf16 ----------------
__global__ __launch_bounds__(256) void kG1(const u16* __restrict__ zbf, const u16* __restrict__ fwbf1,
                                           const float* __restrict__ fb,
                                           float* __restrict__ h1, u16* __restrict__ gbf) {
    int n0 = blockIdx.x * 64, m0 = blockIdx.y * 16;
    int tid = threadIdx.x, wv = tid >> 6, lane = tid & 63, row = lane & 15, kg = lane >> 4;
    const u16* zr = zbf + (size_t)(m0 + row) * 192;
    const u16* wr = fwbf1 + (size_t)(n0 + wv*16 + row) * 192;
    f32x4 acc = (f32x4){0.f,0.f,0.f,0.f};
    #pragma unroll
    for (int ks = 0; ks < 6; ++ks) {
        bf16x8 av = *(const bf16x8*)(zr + ks*32 + kg*8);
        bf16x8 bv = *(const bf16x8*)(wr + ks*32 + kg*8);
        acc = __builtin_amdgcn_mfma_f32_16x16x32_bf16(av, bv, acc, 0, 0, 0);
    }
    int n = n0 + wv*16 + row;
    float bias = fb[n];
    #pragma unroll
    for (int r = 0; r < 4; ++r) {
        int m = m0 + kg*4 + r;
        float v = acc[r] + bias;
        h1[(size_t)m*PROJ + n] = v;
        float ge = 0.5f * v * (1.f + erff(v * 0.70710678118f));
        gbf[(size_t)m*PROJ + n] = f2bf(ge);
    }
}

// ---------------- kG2: h2 = h1 + g @ fc2_w^T + b (MFMA) ----------------
__global__ __launch_bounds__(256) void kG2(const u16* __restrict__ gbf, const u16* __restrict__ fwbf,
                                           const float* __restrict__ fb, const float* __restrict__ h1,
                                           float* __restrict__ h2) {
    int n0 = blockIdx.x * 32, m0 = blockIdx.y * 64;
    int tid = threadIdx.x;
    int wv = tid >> 6, lane = tid & 63, row = lane & 15, kg = lane >> 4;
    const u16* gr = gbf + (size_t)(m0 + wv*16 + row) * PROJ;
    f32x4 acc[2];
    #pragma unroll
    for (int i = 0; i < 2; ++i) acc[i] = (f32x4){0.f,0.f,0.f,0.f};
    for (int ks = 0; ks < 32; ++ks) {
        int kbase = ks*32 + kg*8;
        bf16x8 av  = *(const bf16x8*)(gr + kbase);
        bf16x8 bv0 = *(const bf16x8*)(fwbf + (size_t)(n0      + row)*PROJ + kbase);
        bf16x8 bv1 = *(const bf16x8*)(fwbf + (size_t)(n0 + 16 + row)*PROJ + kbase);
        acc[0] = __builtin_amdgcn_mfma_f32_16x16x32_bf16(av, bv0, acc[0], 0, 0, 0);
        acc[1] = __builtin_amdgcn_mfma_f32_16x16x32_bf16(av, bv1, acc[1], 0, 0, 0);
    }
    int m = m0 + wv*16 + kg*4;
    #pragma unroll
    for (int nf = 0; nf < 2; ++nf) {
        int n = n0 + nf*16 + row;
        float bias = fb[n];
        #pragma unroll
        for (int r = 0; r < 4; ++r)
            h2[(size_t)(m + r)*PROJ + n] = acc[nf][r] + bias + h1[(size_t)(m + r)*PROJ + n];
    }
}

// ---------------- kG3: LayerNorm rows of 1024 ----------------
__global__ __launch_bounds__(256) void kG3(const float* __restrict__ h2, const float* __restrict__ lg,
                                           const float* __restrict__ lb, float* __restrict__ out) {
    int b = blockIdx.x, tid = threadIdx.x;
    float4 v = *(const float4*)&h2[(size_t)b*PROJ + tid*4];
    float s = v.x + v.y + v.z + v.w;
    float q = v.x*v.x + v.y*v.y + v.z*v.z + v.w*v.w;
    __shared__ float ps[4], pq[4], mb[2];
    int wave = tid >> 6, lane = tid & 63;
    #pragma unroll
    for (int d = 32; d >= 1; d >>= 1) { s += __shfl_down(s, d); q += __shfl_down(q, d); }
    if (lane == 0) { ps[wave] = s; pq[wave] = q; }
    __syncthreads();
    if (tid == 0) {
        float S = ps[0]+ps[1]+ps[2]+ps[3], Q = pq[0]+pq[1]+pq[2]+pq[3];
        float mean = S / 1024.f, var = Q / 1024.f - mean*mean;
        mb[0] = mean; mb[1] = rsqrtf(var + 1e-5f);
    }
    __syncthreads();
    float mean = mb[0], inv = mb[1];
    float4 g4 = *(const float4*)&lg[tid*4];
    float4 b4 = *(const float4*)&lb[tid*4];
    float4 o4;
    o4.x = (v.x - mean)*inv*g4.x + b4.x;
    o4.y = (v.y - mean)*inv*g4.y + b4.y;
    o4.z = (v.z - mean)*inv*g4.z + b4.z;
    o4.w = (v.w - mean)*inv*g4.w + b4.w;
    *(float4*)&out[(size_t)b*PROJ + tid*4] = o4;
}

extern "C" void kernel_launch(void* const* d_in, const int* in_sizes, int n_in,
                              void* d_out, int out_size, void* d_ws, size_t ws_size,
                              hipStream_t stream) {
    const float* x       = (const float*)d_in[0];
    const int*   subjects= (const int*)  d_in[1];
    const float* W_subj  = (const float*)d_in[2];
    const float* b_subj  = (const float*)d_in[3];
    const float* conv1_w = (const float*)d_in[4];
    const float* conv1_b = (const float*)d_in[5];
    const float* bn1_g   = (const float*)d_in[6];
    const float* bn1_b   = (const float*)d_in[7];
    const float* conv2_w = (const float*)d_in[8];
    const float* conv2_b = (const float*)d_in[9];
    const float* bn2_g   = (const float*)d_in[10];
    const float* bn2_b   = (const float*)d_in[11];
    const float* proj_w  = (const float*)d_in[12];
    const float* proj_b  = (const float*)d_in[13];
    const float* fc1_w   = (const float*)d_in[14];
    const float* fc1_b   = (const float*)d_in[15];
    const float* fc2_w   = (const float*)d_in[16];
    const float* fc2_b   = (const float*)d_in[17];
    const float* ln_g    = (const float*)d_in[18];
    const float* ln_b    = (const float*)d_in[19];
    float* out = (float*)d_out;

    char* ws = (char*)d_ws;
    u16*   pooled = (u16*)  ws;                      // 118,702,080 B  [b][c][w][o]
    float* out2   = (float*)(ws + 118702144);        // 3,768,320 B
    u16*   zbf    = (u16*)  (ws + 122470464);        // 196,608 B
    float* h1     = (float*)(ws + 122667072);        // 2,097,152 B
    float* h2     = (float*)(ws + 124764224);        // 2,097,152 B
    u16*   gbf    = (u16*)  (ws + 126861376);        // 1,048,576 B
    float* stats  = (float*)(ws + 127909952);        // 1,280 B (pad 4096)
    u16*   Wbf    = (u16*)  (ws + 127914048);        // 1,310,720 B
    u16*   Wbf2   = (u16*)  (ws + 129224768);        // 242,688 B
    u16*   fwbf2  = (u16*)  (ws + 129467456);        // 2,097,152 B
    u16*   fwbf1  = (u16*)  (ws + 131564608);        // 393,216 B

    kX  <<<7898, 256, 0, stream>>>(W_subj, conv2_w, fc1_w, fc2_w, Wbf, Wbf2, fwbf1, fwbf2, stats);
    kAB <<<dim3(512, 2), 256, 0, stream>>>(x, subjects, Wbf, b_subj, conv1_w, conv1_b, pooled, stats);
    kD  <<<736, 256, 0, stream>>>(pooled, Wbf2, conv2_b, bn1_g, bn1_b, stats, out2, stats);
    kF  <<<512, 256, 0, stream>>>(out2, stats, bn2_g, bn2_b, proj_w, proj_b, zbf);
    kG1 <<<dim3(16, 32), 256, 0, stream>>>(zbf, fwbf1, fc1_b, h1, gbf);
    kG2 <<<dim3(32, 8), 256, 0, stream>>>(gbf, fwbf2, fc2_b, h1, h2);
    kG3 <<<512, 256, 0, stream>>>(h2, ln_g, ln_b, out);
    (void)in_sizes; (void)n_in; (void)out_size; (void)ws_size;
}